// Round 12
// baseline (174.407 us; speedup 1.0000x reference)
//
#include <hip/hip_runtime.h>
#include <stdint.h>

typedef unsigned int u32;
typedef unsigned short u16;
typedef __attribute__((ext_vector_type(8))) short v8s;   // 8 bf16 (4 VGPRs)
typedef __attribute__((ext_vector_type(4))) float v4f;   // 4 f32 acc

#define GN_EPS 1e-5f

// ---------- bf16 helpers (intermediates in ws are bf16) ----------
__device__ __forceinline__ float bflo(u32 u){ return __uint_as_float(u << 16); }
__device__ __forceinline__ float bfhi(u32 u){ return __uint_as_float(u & 0xffff0000u); }
__device__ __forceinline__ u16 f2bf(float f){
  u32 x = __float_as_uint(f);
  u32 r = (x + 0x7fffu + ((x >> 16) & 1u)) >> 16;   // RNE
  return (u16)r;
}
__device__ __forceinline__ u32 pack2(float a, float b){
  return (u32)f2bf(a) | ((u32)f2bf(b) << 16);
}
__device__ __forceinline__ void unpack8(const uint4 u, float* f){
  f[0]=bflo(u.x); f[1]=bfhi(u.x); f[2]=bflo(u.y); f[3]=bfhi(u.y);
  f[4]=bflo(u.z); f[5]=bfhi(u.z); f[6]=bflo(u.w); f[7]=bfhi(u.w);
}
// load 8 f32, return packed bf16 (4 u32)
__device__ __forceinline__ uint4 loadpack8(const float* __restrict__ p){
  float4 a = *(const float4*)p, b = *(const float4*)(p + 4);
  return make_uint4(pack2(a.x,a.y),pack2(a.z,a.w),pack2(b.x,b.y),pack2(b.z,b.w));
}

// batch accessor: int32 or int64 (little-endian low word)
__device__ __forceinline__ int getb(const int* __restrict__ b, int is64, int i){
  return b[is64 ? 2*i : i];
}

// =====================================================================
// K0: detect batch int-width (parallel).
// =====================================================================
__global__ __launch_bounds__(256) void k_detect(
    const int* __restrict__ batch, int n, int* __restrict__ flags)
{
  int i = blockIdx.x*256 + threadIdx.x;
  int bad = 0;
  if (i < n - 1 && batch[i] > batch[i + 1]) bad = 1;
  if (__builtin_amdgcn_ballot_w64(bad) != 0 && (threadIdx.x & 63) == 0)
    atomicOr(&flags[0], 1);
}

// =====================================================================
// K0b: CSR bounds. bounds[g] = first node of graph g; bounds[B] = N.
// =====================================================================
__global__ __launch_bounds__(256) void k_bounds(
    const int* __restrict__ batch, const int* __restrict__ flags,
    int N, int B, int* __restrict__ bounds)
{
  int i = blockIdx.x*256 + threadIdx.x;
  if (i >= N) return;
  const int is64 = flags[0];
  int b = getb(batch, is64, i);
  int prev = (i == 0) ? -1 : getb(batch, is64, i - 1);
  for (int g = prev + 1; g <= b; g++) bounds[g] = i;
  if (i == N - 1)
    for (int g = b + 1; g <= B; g++) bounds[g] = N;
}

// =====================================================================
// K1 (MFMA): y = x @ w_pre^T + b_pre, f32 out. 64x64 tile, 4 waves 2x2.
// =====================================================================
__global__ __launch_bounds__(256) void k_pre(
    const float* __restrict__ x, const float* __restrict__ wpre,
    const float* __restrict__ bpre, float* __restrict__ y, int N, int nbm)
{
  __shared__ __align__(16) u16 As[64*40];
  __shared__ __align__(16) u16 Bs[64*40];
  const int t = threadIdx.x;
  const int bm = blockIdx.x % nbm;
  const int bn = blockIdx.x / nbm;          // 0..3
  const int m_base = bm*64, n_base = bn*64;
  const int w = t >> 6, lane = t & 63;
  const int wm = (w >> 1)*32, wn = (w & 1)*32;
  const int fr = lane & 15, fk = lane >> 4;
  const int srow = t >> 2, scol = (t & 3)*8;

  v4f acc[2][2];
#pragma unroll
  for (int i = 0; i < 2; i++)
#pragma unroll
    for (int j = 0; j < 2; j++) acc[i][j] = (v4f){0.f,0.f,0.f,0.f};

  for (int k0 = 0; k0 < 256; k0 += 32) {
    __syncthreads();
    {
      int gm = m_base + srow;
      uint4 av = make_uint4(0u,0u,0u,0u);
      if (gm < N) av = loadpack8(x + (size_t)gm*256 + k0 + scol);
      *(uint4*)&As[srow*40 + scol] = av;
      uint4 bv = loadpack8(wpre + (size_t)(n_base + srow)*256 + k0 + scol);
      *(uint4*)&Bs[srow*40 + scol] = bv;
    }
    __syncthreads();
    v8s a0 = *(const v8s*)&As[(wm      + fr)*40 + fk*8];
    v8s a1 = *(const v8s*)&As[(wm + 16 + fr)*40 + fk*8];
    v8s b0 = *(const v8s*)&Bs[(wn      + fr)*40 + fk*8];
    v8s b1 = *(const v8s*)&Bs[(wn + 16 + fr)*40 + fk*8];
    acc[0][0] = __builtin_amdgcn_mfma_f32_16x16x32_bf16(a0,b0,acc[0][0],0,0,0);
    acc[0][1] = __builtin_amdgcn_mfma_f32_16x16x32_bf16(a0,b1,acc[0][1],0,0,0);
    acc[1][0] = __builtin_amdgcn_mfma_f32_16x16x32_bf16(a1,b0,acc[1][0],0,0,0);
    acc[1][1] = __builtin_amdgcn_mfma_f32_16x16x32_bf16(a1,b1,acc[1][1],0,0,0);
  }
#pragma unroll
  for (int nj = 0; nj < 2; nj++) {
    int col = n_base + wn + nj*16 + fr;
    float bpv = bpre[col];
#pragma unroll
    for (int mi = 0; mi < 2; mi++) {
#pragma unroll
      for (int r = 0; r < 4; r++) {
        int row = m_base + wm + mi*16 + fk*4 + r;
        if (row < N) y[(size_t)row*256 + col] = acc[mi][nj][r] + bpv;
      }
    }
  }
}

// =====================================================================
// K2: block = (group g, 256-node chunk). Weight reads wave-uniform.
// =====================================================================
__global__ __launch_bounds__(256) void k_gnqkv(
    const float* __restrict__ y, const float* __restrict__ wq,
    const float* __restrict__ wk, const float* __restrict__ wv,
    u16* __restrict__ qo, u16* __restrict__ ko, u16* __restrict__ vo, int N)
{
  __shared__ __align__(16) float wL[3*512];
  const int t = threadIdx.x;
  const int g = blockIdx.x & 15;
  const int c = blockIdx.x >> 4;
  {
    const float* srcs[3] = {wq, wk, wv};
#pragma unroll
    for (int tz = 0; tz < 3; tz++) {
      wL[tz*512 + t]       = srcs[tz][g*512 + t];
      wL[tz*512 + t + 256] = srcs[tz][g*512 + t + 256];
    }
  }
  __syncthreads();
  const int node = c*256 + t;
  if (node >= N) return;

  const float* yp = y + (size_t)node*256 + g*16;
  float4 v0 = *(const float4*)yp;
  float4 v1 = *(const float4*)(yp + 4);
  float4 v2 = *(const float4*)(yp + 8);
  float4 v3 = *(const float4*)(yp + 12);
  float a[16] = {v0.x,v0.y,v0.z,v0.w, v1.x,v1.y,v1.z,v1.w,
                 v2.x,v2.y,v2.z,v2.w, v3.x,v3.y,v3.z,v3.w};
  float mu = 0.f;
#pragma unroll
  for (int i = 0; i < 16; i++) mu += a[i];
  mu *= 0.0625f;
  float s2 = 0.f;
#pragma unroll
  for (int i = 0; i < 16; i++) { float d = a[i]-mu; s2 = fmaf(d,d,s2); }
  float inv = rsqrtf(s2*0.0625f + GN_EPS);
  float yn[16];
#pragma unroll
  for (int i = 0; i < 16; i++) yn[i] = (a[i]-mu)*inv;

  u16* outs[3] = {qo, ko, vo};
#pragma unroll
  for (int tz = 0; tz < 3; tz++) {
#pragma unroll
    for (int s = 0; s < 2; s++) {
      u32 p[8];
#pragma unroll
      for (int o = 0; o < 16; o++) {
        const float* row = &wL[tz*512 + (s*16 + o)*16];
        float4 W0 = *(const float4*)row;
        float4 W1 = *(const float4*)(row + 4);
        float4 W2 = *(const float4*)(row + 8);
        float4 W3 = *(const float4*)(row + 12);
        float w[16] = {W0.x,W0.y,W0.z,W0.w,W1.x,W1.y,W1.z,W1.w,
                       W2.x,W2.y,W2.z,W2.w,W3.x,W3.y,W3.z,W3.w};
        float d = 0.f;
#pragma unroll
        for (int i = 0; i < 16; i++) d = fmaf(yn[i], w[i], d);
        if (tz < 2) d = __expf(d*0.25f);
        if (o & 1) p[o>>1] |= (u32)f2bf(d) << 16;
        else       p[o>>1]  = (u32)f2bf(d);
      }
      u16* dst = outs[tz] + (size_t)node*512 + g*32 + s*16;
      *(uint4*)dst       = make_uint4(p[0],p[1],p[2],p[3]);
      *(uint4*)(dst + 8) = make_uint4(p[4],p[5],p[6],p[7]);
    }
  }
}

// =====================================================================
// K3a (k_segkv): phases 1+2. 4 blocks/graph, 8 heads each.
// Outputs: out1 (f32), kvp (bf16 compact copy), kssg (f32 ksum).
// =====================================================================
__global__ __launch_bounds__(256) void k_segkv(
    const u16* __restrict__ xk, const u16* __restrict__ xv,
    const float* __restrict__ xres, const int* __restrict__ bounds,
    float* __restrict__ out1, u16* __restrict__ kvp,
    float* __restrict__ kssg, int N)
{
  __shared__ __align__(16) float red[2*2592];   // 2 slabs [nh]*324+[h]*20
  __shared__ float ksred[2*130];
  const int t = threadIdx.x;
  const int b  = blockIdx.x >> 2;
  const int H0 = (blockIdx.x & 3) * 8;
  const int lo = bounds[b], hi = bounds[b+1];
  const int ns = t >> 6, nh = (t >> 3) & 7, hp = t & 7;

  float kv[2][16];
#pragma unroll
  for (int r = 0; r < 2; r++)
#pragma unroll
    for (int v = 0; v < 16; v++) kv[r][v] = 0.f;
  float ks0 = 0.f, ks1 = 0.f;

  // ---- phase 1: prefetched direct-from-global accumulation ----
  const size_t koff = (size_t)(H0 + nh)*16 + 2*hp;
  const size_t voff = (size_t)(H0 + nh)*16;
  int node = lo + ns;
  u32 kw = 0; uint4 V0 = make_uint4(0,0,0,0), V1 = make_uint4(0,0,0,0);
  if (node < hi) {
    kw = *(const u32*) (xk + (size_t)node*512 + koff);
    V0 = *(const uint4*)(xv + (size_t)node*512 + voff);
    V1 = *(const uint4*)(xv + (size_t)node*512 + voff + 8);
  }
  while (node < hi) {
    int nxt = node + 4;
    u32 kwn = 0; uint4 V0n = make_uint4(0,0,0,0), V1n = make_uint4(0,0,0,0);
    if (nxt < hi) {
      kwn = *(const u32*) (xk + (size_t)nxt*512 + koff);
      V0n = *(const uint4*)(xv + (size_t)nxt*512 + voff);
      V1n = *(const uint4*)(xv + (size_t)nxt*512 + voff + 8);
    }
    float k0 = bflo(kw), k1 = bfhi(kw);
    float vf[16]; unpack8(V0, vf); unpack8(V1, vf + 8);
    ks0 += k0; ks1 += k1;
#pragma unroll
    for (int v = 0; v < 16; v++) {
      kv[0][v] = fmaf(k0, vf[v], kv[0][v]);
      kv[1][v] = fmaf(k1, vf[v], kv[1][v]);
    }
    kw = kwn; V0 = V0n; V1 = V1n; node = nxt;
  }

  // ---- reduce across 4 node-slots (2-step tree) ----
  if (ns >= 2) {
    float* s = &red[(ns - 2)*2592];
#pragma unroll
    for (int r = 0; r < 2; r++) {
      float* rp = &s[nh*324 + (2*hp + r)*20];
      *(float4*)rp       = make_float4(kv[r][0], kv[r][1], kv[r][2], kv[r][3]);
      *(float4*)(rp + 4) = make_float4(kv[r][4], kv[r][5], kv[r][6], kv[r][7]);
      *(float4*)(rp + 8) = make_float4(kv[r][8], kv[r][9], kv[r][10],kv[r][11]);
      *(float4*)(rp + 12)= make_float4(kv[r][12],kv[r][13],kv[r][14],kv[r][15]);
    }
    ksred[(ns-2)*130 + nh*16 + 2*hp]     = ks0;
    ksred[(ns-2)*130 + nh*16 + 2*hp + 1] = ks1;
  }
  __syncthreads();
  if (ns < 2) {
    const float* s = &red[ns*2592];
#pragma unroll
    for (int r = 0; r < 2; r++) {
      const float* rp = &s[nh*324 + (2*hp + r)*20];
      float4 R0 = *(const float4*)rp;
      float4 R1 = *(const float4*)(rp + 4);
      float4 R2 = *(const float4*)(rp + 8);
      float4 R3 = *(const float4*)(rp + 12);
      kv[r][0] += R0.x; kv[r][1] += R0.y; kv[r][2] += R0.z; kv[r][3] += R0.w;
      kv[r][4] += R1.x; kv[r][5] += R1.y; kv[r][6] += R1.z; kv[r][7] += R1.w;
      kv[r][8] += R2.x; kv[r][9] += R2.y; kv[r][10]+= R2.z; kv[r][11]+= R2.w;
      kv[r][12]+= R3.x; kv[r][13]+= R3.y; kv[r][14]+= R3.z; kv[r][15]+= R3.w;
    }
    ks0 += ksred[ns*130 + nh*16 + 2*hp];
    ks1 += ksred[ns*130 + nh*16 + 2*hp + 1];
  }
  __syncthreads();
  if (ns == 1) {
#pragma unroll
    for (int r = 0; r < 2; r++) {
      float* rp = &red[nh*324 + (2*hp + r)*20];
      *(float4*)rp       = make_float4(kv[r][0], kv[r][1], kv[r][2], kv[r][3]);
      *(float4*)(rp + 4) = make_float4(kv[r][4], kv[r][5], kv[r][6], kv[r][7]);
      *(float4*)(rp + 8) = make_float4(kv[r][8], kv[r][9], kv[r][10],kv[r][11]);
      *(float4*)(rp + 12)= make_float4(kv[r][12],kv[r][13],kv[r][14],kv[r][15]);
    }
    ksred[nh*16 + 2*hp]     = ks0;
    ksred[nh*16 + 2*hp + 1] = ks1;
  }
  __syncthreads();
  if (ns == 0) {
#pragma unroll
    for (int r = 0; r < 2; r++) {
      const float* rp = &red[nh*324 + (2*hp + r)*20];
      float4 R0 = *(const float4*)rp;
      float4 R1 = *(const float4*)(rp + 4);
      float4 R2 = *(const float4*)(rp + 8);
      float4 R3 = *(const float4*)(rp + 12);
      kv[r][0] += R0.x; kv[r][1] += R0.y; kv[r][2] += R0.z; kv[r][3] += R0.w;
      kv[r][4] += R1.x; kv[r][5] += R1.y; kv[r][6] += R1.z; kv[r][7] += R1.w;
      kv[r][8] += R2.x; kv[r][9] += R2.y; kv[r][10]+= R2.z; kv[r][11]+= R2.w;
      kv[r][12]+= R3.x; kv[r][13]+= R3.y; kv[r][14]+= R3.z; kv[r][15]+= R3.w;
    }
    ks0 += ksred[nh*16 + 2*hp];
    ks1 += ksred[nh*16 + 2*hp + 1];
    const int head = H0 + nh;
    *(float2*)&kssg[(size_t)b*512 + head*16 + 2*hp] = make_float2(ks0, ks1);

    // ---- phase 2: out1 = kv + xres (f32) + compact bf16 copy ----
#pragma unroll
    for (int r = 0; r < 2; r++) {
      int h = 2*hp + r;
      size_t idx = ((size_t)(b*32 + head)*16 + h)*16;
      const float* xp = xres + idx;
      float4 X0 = *(const float4*)xp;
      float4 X1 = *(const float4*)(xp + 4);
      float4 X2 = *(const float4*)(xp + 8);
      float4 X3 = *(const float4*)(xp + 12);
      float xf[16] = {X0.x,X0.y,X0.z,X0.w,X1.x,X1.y,X1.z,X1.w,
                      X2.x,X2.y,X2.z,X2.w,X3.x,X3.y,X3.z,X3.w};
      float o[16];
#pragma unroll
      for (int j = 0; j < 16; j++) o[j] = kv[r][j] + xf[j];
      float* op = out1 + idx;
      *(float4*)op        = make_float4(o[0],o[1],o[2],o[3]);
      *(float4*)(op + 4)  = make_float4(o[4],o[5],o[6],o[7]);
      *(float4*)(op + 8)  = make_float4(o[8],o[9],o[10],o[11]);
      *(float4*)(op + 12) = make_float4(o[12],o[13],o[14],o[15]);
      u16* kp = kvp + idx;
      *(uint4*)kp       = make_uint4(pack2(o[0],o[1]),  pack2(o[2],o[3]),
                                     pack2(o[4],o[5]),  pack2(o[6],o[7]));
      *(uint4*)(kp + 8) = make_uint4(pack2(o[8],o[9]),  pack2(o[10],o[11]),
                                     pack2(o[12],o[13]),pack2(o[14],o[15]));
    }
  }
}

// =====================================================================
// K3b (k_att3): node-range blocks of 32; per overlapping graph, stage
// kv (bf16, head stride 258 u16 -> odd dword stride, conflict-free) and
// ksum into LDS coalesced; then (node, head) matvec from LDS.
// =====================================================================
__global__ __launch_bounds__(256) void k_att3(
    const u16* __restrict__ xq, const float* __restrict__ kssg,
    const u16* __restrict__ kvp, const int* __restrict__ batch,
    const int* __restrict__ flags, const int* __restrict__ bounds,
    u16* __restrict__ att, int N, int B)
{
  __shared__ __align__(16) u16 kvL[32*258 + 8];  // ~16.6 KB
  __shared__ float ksL[32*17];                   // 2.2 KB
  const int t = threadIdx.x;
  const int n0 = blockIdx.x * 32;
  const int nend = (n0 + 32 < N) ? n0 + 32 : N;
  if (n0 >= N) return;
  const int is64 = flags[0];
  int g0 = getb(batch, is64, n0);
  int g1 = getb(batch, is64, nend - 1);
  g0 = g0 < 0 ? 0 : (g0 >= B ? B - 1 : g0);
  g1 = g1 < g0 ? g0 : (g1 >= B ? B - 1 : g1);

  const int nh = t & 31;
  for (int g = g0; g <= g1; g++) {
    int seg_lo = bounds[g]   > n0   ? bounds[g]   : n0;
    int seg_hi = bounds[g+1] < nend ? bounds[g+1] : nend;
    if (seg_lo >= seg_hi) continue;
    __syncthreads();   // protect LDS reuse across graphs
    {
      const u16* src = kvp + (size_t)g * 8192;
      for (int i = t; i < 1024; i += 256) {     // 8192 elems in 8-chunks
        uint4 v = *(const uint4*)(src + i*8);
        *(uint4*)&kvL[(i >> 5)*258 + (i & 31)*8] = v;
      }
      const float* ks = kssg + (size_t)g * 512;
      for (int i = t; i < 512; i += 256)
        ksL[(i >> 4)*17 + (i & 15)] = ks[i];
    }
    __syncthreads();
#pragma unroll
    for (int it = 0; it < 4; it++) {
      int node = seg_lo + (t >> 5) + it*8;
      if (node >= seg_hi) continue;
      const u16* qp = xq + (size_t)node*512 + nh*16;
      uint4 Q0 = *(const uint4*)qp;
      uint4 Q1 = *(const uint4*)(qp + 8);
      float q[16]; unpack8(Q0, q); unpack8(Q1, q + 8);
      const float* ksp = &ksL[nh*17];
      float denom = 0.f;
#pragma unroll
      for (int i = 0; i < 16; i++) denom = fmaf(q[i], ksp[i], denom);
      float inv = 1.0f / fmaxf(denom, 1e-20f);
      float a[16];
#pragma unroll
      for (int v = 0; v < 16; v++) a[v] = 0.f;
      const u16* kvr = &kvL[nh*258];
#pragma unroll
      for (int h = 0; h < 16; h++) {
        float qh = q[h] * inv;
        uint4 W0 = *(const uint4*)(kvr + h*16);
        uint4 W1 = *(const uint4*)(kvr + h*16 + 8);
        float w[16]; unpack8(W0, w); unpack8(W1, w + 8);
#pragma unroll
        for (int v = 0; v < 16; v++) a[v] = fmaf(qh, w[v], a[v]);
      }
      u32 p[8];
#pragma unroll
      for (int j = 0; j < 8; j++) p[j] = pack2(a[2*j], a[2*j+1]);
      u16* dst = att + (size_t)node*512 + nh*16;
      *(uint4*)dst       = make_uint4(p[0],p[1],p[2],p[3]);
      *(uint4*)(dst + 8) = make_uint4(p[4],p[5],p[6],p[7]);
    }
  }
}

// =====================================================================
// K5 (MFMA): out0 = exp(log_scale) * (att @ w_post^T + b_post), K=512.
// =====================================================================
__global__ __launch_bounds__(256) void k_post(
    const u16* __restrict__ att, const float* __restrict__ wpost,
    const float* __restrict__ bpost, const float* __restrict__ ls,
    float* __restrict__ out0, int N, int nbm)
{
  __shared__ __align__(16) u16 As[64*40];
  __shared__ __align__(16) u16 Bs[64*40];
  const int t = threadIdx.x;
  const int bm = blockIdx.x % nbm;
  const int bn = blockIdx.x / nbm;          // 0..3
  const int m_base = bm*64, n_base = bn*64;
  const int w = t >> 6, lane = t & 63;
  const int wm = (w >> 1)*32, wn = (w & 1)*32;
  const int fr = lane & 15, fk = lane >> 4;
  const int srow = t >> 2, scol = (t & 3)*8;

  v4f acc[2][2];
#pragma unroll
  for (int i = 0; i < 2; i++)
#pragma unroll
    for (int j = 0; j < 2; j++) acc[i][j] = (v4f){0.f,0.f,0.f,0.f};

  for (int k0 = 0; k0 < 512; k0 += 32) {
    __syncthreads();
    {
      int gm = m_base + srow;
      uint4 av = make_uint4(0u,0u,0u,0u);
      if (gm < N) av = *(const uint4*)(att + (size_t)gm*512 + k0 + scol);
      *(uint4*)&As[srow*40 + scol] = av;
      uint4 bv = loadpack8(wpost + (size_t)(n_base + srow)*512 + k0 + scol);
      *(uint4*)&Bs[srow*40 + scol] = bv;
    }
    __syncthreads();
    v8s a0 = *(const v8s*)&As[(wm      + fr)*40 + fk*8];
    v8s a1 = *(const v8s*)&As[(wm + 16 + fr)*40 + fk*8];
    v8s b0 = *(const v8s*)&Bs[(wn      + fr)*40 + fk*8];
    v8s b1 = *(const v8s*)&Bs[(wn + 16 + fr)*40 + fk*8];
    acc[0][0] = __builtin_amdgcn_mfma_f32_16x16x32_bf16(a0,b0,acc[0][0],0,0,0);
    acc[0][1] = __builtin_amdgcn_mfma_f32_16x16x32_bf16(a0,b1,acc[0][1],0,0,0);
    acc[1][0] = __builtin_amdgcn_mfma_f32_16x16x32_bf16(a1,b0,acc[1][0],0,0,0);
    acc[1][1] = __builtin_amdgcn_mfma_f32_16x16x32_bf16(a1,b1,acc[1][1],0,0,0);
  }
#pragma unroll
  for (int nj = 0; nj < 2; nj++) {
    int col = n_base + wn + nj*16 + fr;
    float bpv = bpost[col];
    float e   = __expf(ls[col]);
#pragma unroll
    for (int mi = 0; mi < 2; mi++) {
#pragma unroll
      for (int r = 0; r < 4; r++) {
        int row = m_base + wm + mi*16 + fk*4 + r;
        if (row < N) out0[(size_t)row*256 + col] = e*(acc[mi][nj][r] + bpv);
      }
    }
  }
}

// =====================================================================
extern "C" void kernel_launch(void* const* d_in, const int* in_sizes, int n_in,
                              void* d_out, int out_size, void* d_ws, size_t ws_size,
                              hipStream_t stream)
{
  const float* x     = (const float*)d_in[0];
  const float* xres  = (const float*)d_in[1];
  const int*   batch = (const int*)d_in[2];
  const float* wpre  = (const float*)d_in[4];
  const float* bpre  = (const float*)d_in[5];
  const float* wq    = (const float*)d_in[6];
  const float* wk    = (const float*)d_in[7];
  const float* wv    = (const float*)d_in[8];
  const float* wpost = (const float*)d_in[9];
  const float* bpost = (const float*)d_in[10];
  const float* ls    = (const float*)d_in[11];

  const int N = in_sizes[0] / 256;     // 20000 nodes
  const int B = in_sizes[1] / 8192;    // 1024 graphs
  const int nbm = (N + 63) / 64;       // 313 row tiles
  const int nchunk = (N + 255) / 256;  // 79 node chunks

  char* ws = (char*)d_ws;
  size_t off = 0;
  int*   flags  = (int*)(ws + off); off += 256;
  int*   bounds = (int*)(ws + off); off += ((size_t)B + 64) * 4;
  float* y      = (float*)(ws + off);                          // reused for att
  u16*   att    = (u16*)(ws + off);  off += (size_t)N * 1024;
  u16*   q      = (u16*)(ws + off);  off += (size_t)N * 1024;
  u16*   kten   = (u16*)(ws + off);  off += (size_t)N * 1024;
  u16*   vten   = (u16*)(ws + off);  off += (size_t)N * 1024;
  u16*   kvp    = (u16*)(ws + off);  off += (size_t)B * 16384; // B*32*256 bf16
  float* kssg   = (float*)(ws + off); off += (size_t)B * 2048; // B*512 f32

  float* out0 = (float*)d_out;
  float* out1 = out0 + (size_t)N * 256;

  hipMemsetAsync(flags, 0, 4, stream);
  k_detect<<<nchunk,         256, 0, stream>>>(batch, N, flags);
  k_bounds<<<nchunk,         256, 0, stream>>>(batch, flags, N, B, bounds);
  k_pre   <<<nbm * 4,        256, 0, stream>>>(x, wpre, bpre, y, N, nbm);
  k_gnqkv <<<nchunk * 16,    256, 0, stream>>>(y, wq, wk, wv, q, kten, vten, N);
  k_segkv <<<B * 4,          256, 0, stream>>>(kten, vten, xres, bounds,
                                               out1, kvp, kssg, N);
  k_att3  <<<(N + 31) / 32,  256, 0, stream>>>(q, kssg, kvp, batch, flags, bounds,
                                               att, N, B);
  k_post  <<<nbm * 4,        256, 0, stream>>>(att, wpost, bpost, ls, out0, N, nbm);
}

// Round 13
// 136.867 us; speedup vs baseline: 1.2743x; 1.2743x over previous
//
#include <hip/hip_runtime.h>
#include <stdint.h>

typedef unsigned int u32;
typedef unsigned short u16;
typedef __attribute__((ext_vector_type(8))) short v8s;   // 8 bf16 (4 VGPRs)
typedef __attribute__((ext_vector_type(4))) float v4f;   // 4 f32 acc

#define GN_EPS 1e-5f

// ---------- bf16 helpers (intermediates in ws are bf16) ----------
__device__ __forceinline__ float bflo(u32 u){ return __uint_as_float(u << 16); }
__device__ __forceinline__ float bfhi(u32 u){ return __uint_as_float(u & 0xffff0000u); }
__device__ __forceinline__ u16 f2bf(float f){
  u32 x = __float_as_uint(f);
  u32 r = (x + 0x7fffu + ((x >> 16) & 1u)) >> 16;   // RNE
  return (u16)r;
}
__device__ __forceinline__ u32 pack2(float a, float b){
  return (u32)f2bf(a) | ((u32)f2bf(b) << 16);
}
__device__ __forceinline__ void unpack8(const uint4 u, float* f){
  f[0]=bflo(u.x); f[1]=bfhi(u.x); f[2]=bflo(u.y); f[3]=bfhi(u.y);
  f[4]=bflo(u.z); f[5]=bfhi(u.z); f[6]=bflo(u.w); f[7]=bfhi(u.w);
}
// load 8 f32, return packed bf16 (4 u32)
__device__ __forceinline__ uint4 loadpack8(const float* __restrict__ p){
  float4 a = *(const float4*)p, b = *(const float4*)(p + 4);
  return make_uint4(pack2(a.x,a.y),pack2(a.z,a.w),pack2(b.x,b.y),pack2(b.z,b.w));
}

// batch accessor: int32 or int64 (little-endian low word)
__device__ __forceinline__ int getb(const int* __restrict__ b, int is64, int i){
  return b[is64 ? 2*i : i];
}

// =====================================================================
// K0: detect batch int-width (parallel).
// =====================================================================
__global__ __launch_bounds__(256) void k_detect(
    const int* __restrict__ batch, int n, int* __restrict__ flags)
{
  int i = blockIdx.x*256 + threadIdx.x;
  int bad = 0;
  if (i < n - 1 && batch[i] > batch[i + 1]) bad = 1;
  if (__builtin_amdgcn_ballot_w64(bad) != 0 && (threadIdx.x & 63) == 0)
    atomicOr(&flags[0], 1);
}

// =====================================================================
// K0b: CSR bounds. bounds[g] = first node of graph g; bounds[B] = N.
// =====================================================================
__global__ __launch_bounds__(256) void k_bounds(
    const int* __restrict__ batch, const int* __restrict__ flags,
    int N, int B, int* __restrict__ bounds)
{
  int i = blockIdx.x*256 + threadIdx.x;
  if (i >= N) return;
  const int is64 = flags[0];
  int b = getb(batch, is64, i);
  int prev = (i == 0) ? -1 : getb(batch, is64, i - 1);
  for (int g = prev + 1; g <= b; g++) bounds[g] = i;
  if (i == N - 1)
    for (int g = b + 1; g <= B; g++) bounds[g] = N;
}

// =====================================================================
// K1 (MFMA): y = x @ w_pre^T + b_pre, f32 out. Tile 128x64, 4 waves
// (2 row x 2 col), wave tile 64x32 (acc 4x2), BK=32, K=256.
// =====================================================================
__global__ __launch_bounds__(256) void k_pre(
    const float* __restrict__ x, const float* __restrict__ wpre,
    const float* __restrict__ bpre, float* __restrict__ y, int N, int nbm)
{
  __shared__ __align__(16) u16 As[128*40];
  __shared__ __align__(16) u16 Bs[64*40];
  const int t = threadIdx.x;
  const int bm = blockIdx.x % nbm;
  const int bn = blockIdx.x / nbm;          // 0..3
  const int m_base = bm*128, n_base = bn*64;
  const int w = t >> 6, lane = t & 63;
  const int wr = (w >> 1)*64, wc = (w & 1)*32;
  const int fr = lane & 15, fk = lane >> 4;
  const int arow = t >> 1, acol = (t & 1)*16;   // As staging
  const int brow = t >> 2, bcol = (t & 3)*8;    // Bs staging

  v4f acc[4][2];
#pragma unroll
  for (int i = 0; i < 4; i++)
#pragma unroll
    for (int j = 0; j < 2; j++) acc[i][j] = (v4f){0.f,0.f,0.f,0.f};

  for (int k0 = 0; k0 < 256; k0 += 32) {
    __syncthreads();
    {
      int gm = m_base + arow;
      uint4 a0 = make_uint4(0u,0u,0u,0u), a1 = make_uint4(0u,0u,0u,0u);
      if (gm < N) {
        a0 = loadpack8(x + (size_t)gm*256 + k0 + acol);
        a1 = loadpack8(x + (size_t)gm*256 + k0 + acol + 8);
      }
      *(uint4*)&As[arow*40 + acol]     = a0;
      *(uint4*)&As[arow*40 + acol + 8] = a1;
      uint4 bv = loadpack8(wpre + (size_t)(n_base + brow)*256 + k0 + bcol);
      *(uint4*)&Bs[brow*40 + bcol] = bv;
    }
    __syncthreads();
    v8s b0 = *(const v8s*)&Bs[(wc      + fr)*40 + fk*8];
    v8s b1 = *(const v8s*)&Bs[(wc + 16 + fr)*40 + fk*8];
#pragma unroll
    for (int mi = 0; mi < 4; mi++) {
      v8s a = *(const v8s*)&As[(wr + mi*16 + fr)*40 + fk*8];
      acc[mi][0] = __builtin_amdgcn_mfma_f32_16x16x32_bf16(a,b0,acc[mi][0],0,0,0);
      acc[mi][1] = __builtin_amdgcn_mfma_f32_16x16x32_bf16(a,b1,acc[mi][1],0,0,0);
    }
  }
#pragma unroll
  for (int nj = 0; nj < 2; nj++) {
    int col = n_base + wc + nj*16 + fr;
    float bpv = bpre[col];
#pragma unroll
    for (int mi = 0; mi < 4; mi++) {
#pragma unroll
      for (int r = 0; r < 4; r++) {
        int row = m_base + wr + mi*16 + fk*4 + r;
        if (row < N) y[(size_t)row*256 + col] = acc[mi][nj][r] + bpv;
      }
    }
  }
}

// =====================================================================
// K2: block = (group g, 256-node chunk). Weight reads wave-uniform.
// =====================================================================
__global__ __launch_bounds__(256) void k_gnqkv(
    const float* __restrict__ y, const float* __restrict__ wq,
    const float* __restrict__ wk, const float* __restrict__ wv,
    u16* __restrict__ qo, u16* __restrict__ ko, u16* __restrict__ vo, int N)
{
  __shared__ __align__(16) float wL[3*512];
  const int t = threadIdx.x;
  const int g = blockIdx.x & 15;
  const int c = blockIdx.x >> 4;
  {
    const float* srcs[3] = {wq, wk, wv};
#pragma unroll
    for (int tz = 0; tz < 3; tz++) {
      wL[tz*512 + t]       = srcs[tz][g*512 + t];
      wL[tz*512 + t + 256] = srcs[tz][g*512 + t + 256];
    }
  }
  __syncthreads();
  const int node = c*256 + t;
  if (node >= N) return;

  const float* yp = y + (size_t)node*256 + g*16;
  float4 v0 = *(const float4*)yp;
  float4 v1 = *(const float4*)(yp + 4);
  float4 v2 = *(const float4*)(yp + 8);
  float4 v3 = *(const float4*)(yp + 12);
  float a[16] = {v0.x,v0.y,v0.z,v0.w, v1.x,v1.y,v1.z,v1.w,
                 v2.x,v2.y,v2.z,v2.w, v3.x,v3.y,v3.z,v3.w};
  float mu = 0.f;
#pragma unroll
  for (int i = 0; i < 16; i++) mu += a[i];
  mu *= 0.0625f;
  float s2 = 0.f;
#pragma unroll
  for (int i = 0; i < 16; i++) { float d = a[i]-mu; s2 = fmaf(d,d,s2); }
  float inv = rsqrtf(s2*0.0625f + GN_EPS);
  float yn[16];
#pragma unroll
  for (int i = 0; i < 16; i++) yn[i] = (a[i]-mu)*inv;

  u16* outs[3] = {qo, ko, vo};
#pragma unroll
  for (int tz = 0; tz < 3; tz++) {
#pragma unroll
    for (int s = 0; s < 2; s++) {
      u32 p[8];
#pragma unroll
      for (int o = 0; o < 16; o++) {
        const float* row = &wL[tz*512 + (s*16 + o)*16];
        float4 W0 = *(const float4*)row;
        float4 W1 = *(const float4*)(row + 4);
        float4 W2 = *(const float4*)(row + 8);
        float4 W3 = *(const float4*)(row + 12);
        float w[16] = {W0.x,W0.y,W0.z,W0.w,W1.x,W1.y,W1.z,W1.w,
                       W2.x,W2.y,W2.z,W2.w,W3.x,W3.y,W3.z,W3.w};
        float d = 0.f;
#pragma unroll
        for (int i = 0; i < 16; i++) d = fmaf(yn[i], w[i], d);
        if (tz < 2) d = __expf(d*0.25f);
        if (o & 1) p[o>>1] |= (u32)f2bf(d) << 16;
        else       p[o>>1]  = (u32)f2bf(d);
      }
      u16* dst = outs[tz] + (size_t)node*512 + g*32 + s*16;
      *(uint4*)dst       = make_uint4(p[0],p[1],p[2],p[3]);
      *(uint4*)(dst + 8) = make_uint4(p[4],p[5],p[6],p[7]);
    }
  }
}

// =====================================================================
// K3 (512 threads, fused — round-8 version): per-graph segment-sum +
// att. Phase 1 two node-halves; reduce via LDS; phase 2 out1+LDS kv;
// phase 3 att from LDS-resident kv.
// =====================================================================
__global__ __launch_bounds__(512) void k_segatt(
    const u16* __restrict__ xk, const u16* __restrict__ xv,
    const u16* __restrict__ xq, const float* __restrict__ xres,
    const int* __restrict__ bounds,
    float* __restrict__ out1, u16* __restrict__ att, int N)
{
  __shared__ __align__(16) float red[512*20];   // 40 KB
  __shared__ __align__(16) float kspart[512];   // 2 KB
  __shared__ __align__(16) u16 kvs[32*280];     // 17.5 KB
  __shared__ float kss[32*17];                  // 2.2 KB
  const int b = blockIdx.x, t = threadIdx.x;
  const int lo = bounds[b], hi = bounds[b+1];
  const int half = t >> 8;
  const int nh = (t >> 3) & 31, hp = t & 7;

  float kv[2][16];
#pragma unroll
  for (int r = 0; r < 2; r++)
#pragma unroll
    for (int v = 0; v < 16; v++) kv[r][v] = 0.f;
  float ks0 = 0.f, ks1 = 0.f;

  // ---- phase 1: direct-from-global, interleaved halves, unroll x2 ----
  const size_t koff = (size_t)nh*16 + 2*hp;
  const size_t voff = (size_t)nh*16;
  int node = lo + half;
  for (; node + 2 < hi; node += 4) {
    u32  kw0 = *(const u32*) (xk + (size_t)node*512 + koff);
    uint4 Va0 = *(const uint4*)(xv + (size_t)node*512 + voff);
    uint4 Va1 = *(const uint4*)(xv + (size_t)node*512 + voff + 8);
    u32  kw1 = *(const u32*) (xk + (size_t)(node+2)*512 + koff);
    uint4 Vb0 = *(const uint4*)(xv + (size_t)(node+2)*512 + voff);
    uint4 Vb1 = *(const uint4*)(xv + (size_t)(node+2)*512 + voff + 8);
    float a0 = bflo(kw0), a1 = bfhi(kw0);
    float b0 = bflo(kw1), b1 = bfhi(kw1);
    float va[16], vb[16];
    unpack8(Va0, va); unpack8(Va1, va + 8);
    unpack8(Vb0, vb); unpack8(Vb1, vb + 8);
    ks0 += a0 + b0; ks1 += a1 + b1;
#pragma unroll
    for (int v = 0; v < 16; v++) {
      kv[0][v] = fmaf(a0, va[v], kv[0][v]);
      kv[1][v] = fmaf(a1, va[v], kv[1][v]);
      kv[0][v] = fmaf(b0, vb[v], kv[0][v]);
      kv[1][v] = fmaf(b1, vb[v], kv[1][v]);
    }
  }
  if (node < hi) {
    u32  kw = *(const u32*) (xk + (size_t)node*512 + koff);
    uint4 V0 = *(const uint4*)(xv + (size_t)node*512 + voff);
    uint4 V1 = *(const uint4*)(xv + (size_t)node*512 + voff + 8);
    float k0 = bflo(kw), k1 = bfhi(kw);
    float vf[16]; unpack8(V0, vf); unpack8(V1, vf + 8);
    ks0 += k0; ks1 += k1;
#pragma unroll
    for (int v = 0; v < 16; v++) {
      kv[0][v] = fmaf(k0, vf[v], kv[0][v]);
      kv[1][v] = fmaf(k1, vf[v], kv[1][v]);
    }
  }

  // ---- reduce halves ----
  if (half == 0) {
#pragma unroll
    for (int r = 0; r < 2; r++) {
      float* rp = &red[(nh*16 + 2*hp + r)*20];
      *(float4*)rp       = make_float4(kv[r][0], kv[r][1], kv[r][2], kv[r][3]);
      *(float4*)(rp + 4) = make_float4(kv[r][4], kv[r][5], kv[r][6], kv[r][7]);
      *(float4*)(rp + 8) = make_float4(kv[r][8], kv[r][9], kv[r][10],kv[r][11]);
      *(float4*)(rp + 12)= make_float4(kv[r][12],kv[r][13],kv[r][14],kv[r][15]);
    }
    kspart[nh*16 + 2*hp]     = ks0;
    kspart[nh*16 + 2*hp + 1] = ks1;
  }
  __syncthreads();

  if (half == 1) {
#pragma unroll
    for (int r = 0; r < 2; r++) {
      const float* rp = &red[(nh*16 + 2*hp + r)*20];
      float4 R0 = *(const float4*)rp;
      float4 R1 = *(const float4*)(rp + 4);
      float4 R2 = *(const float4*)(rp + 8);
      float4 R3 = *(const float4*)(rp + 12);
      kv[r][0] += R0.x; kv[r][1] += R0.y; kv[r][2] += R0.z; kv[r][3] += R0.w;
      kv[r][4] += R1.x; kv[r][5] += R1.y; kv[r][6] += R1.z; kv[r][7] += R1.w;
      kv[r][8] += R2.x; kv[r][9] += R2.y; kv[r][10]+= R2.z; kv[r][11]+= R2.w;
      kv[r][12]+= R3.x; kv[r][13]+= R3.y; kv[r][14]+= R3.z; kv[r][15]+= R3.w;
    }
    ks0 += kspart[nh*16 + 2*hp];
    ks1 += kspart[nh*16 + 2*hp + 1];
    kss[nh*17 + 2*hp]     = ks0;
    kss[nh*17 + 2*hp + 1] = ks1;

    // ---- phase 2: out1 = kv + xres; kv -> LDS (bf16) ----
#pragma unroll
    for (int r = 0; r < 2; r++) {
      int h = 2*hp + r;
      size_t idx = ((size_t)(b*32 + nh)*16 + h)*16;
      const float* xp = xres + idx;
      float4 X0 = *(const float4*)xp;
      float4 X1 = *(const float4*)(xp + 4);
      float4 X2 = *(const float4*)(xp + 8);
      float4 X3 = *(const float4*)(xp + 12);
      float xf[16] = {X0.x,X0.y,X0.z,X0.w,X1.x,X1.y,X1.z,X1.w,
                      X2.x,X2.y,X2.z,X2.w,X3.x,X3.y,X3.z,X3.w};
      float o[16];
#pragma unroll
      for (int j = 0; j < 16; j++) o[j] = kv[r][j] + xf[j];
      float* op = out1 + idx;
      *(float4*)op        = make_float4(o[0],o[1],o[2],o[3]);
      *(float4*)(op + 4)  = make_float4(o[4],o[5],o[6],o[7]);
      *(float4*)(op + 8)  = make_float4(o[8],o[9],o[10],o[11]);
      *(float4*)(op + 12) = make_float4(o[12],o[13],o[14],o[15]);
      u16* lp = &kvs[nh*280 + h*16];
      *(uint4*)lp       = make_uint4(pack2(o[0],o[1]),  pack2(o[2],o[3]),
                                     pack2(o[4],o[5]),  pack2(o[6],o[7]));
      *(uint4*)(lp + 8) = make_uint4(pack2(o[8],o[9]),  pack2(o[10],o[11]),
                                     pack2(o[12],o[13]),pack2(o[14],o[15]));
    }
  }
  __syncthreads();

  // ---- phase 3: att, 16 node-slots per iter ----
  const int nh2 = t & 31, ns = t >> 5;   // ns 0..15
  for (int n0 = lo; n0 < hi; n0 += 16) {
    int nodei = n0 + ns;
    if (nodei >= hi) continue;
    const u16* qp = xq + (size_t)nodei*512 + nh2*16;
    uint4 Q0 = *(const uint4*)qp;
    uint4 Q1 = *(const uint4*)(qp + 8);
    float q[16]; unpack8(Q0, q); unpack8(Q1, q + 8);
    const float* ksp = &kss[nh2*17];
    float denom = 0.f;
#pragma unroll
    for (int i = 0; i < 16; i++) denom = fmaf(q[i], ksp[i], denom);
    float inv = 1.0f / fmaxf(denom, 1e-20f);
    float a[16];
#pragma unroll
    for (int v = 0; v < 16; v++) a[v] = 0.f;
    const u16* kvp = &kvs[nh2*280];
#pragma unroll
    for (int h = 0; h < 16; h++) {
      float qh = q[h] * inv;
      uint4 W0 = *(const uint4*)(kvp + h*16);
      uint4 W1 = *(const uint4*)(kvp + h*16 + 8);
      float w[16]; unpack8(W0, w); unpack8(W1, w + 8);
#pragma unroll
      for (int v = 0; v < 16; v++) a[v] = fmaf(qh, w[v], a[v]);
    }
    u32 p[8];
#pragma unroll
    for (int j = 0; j < 8; j++) p[j] = pack2(a[2*j], a[2*j+1]);
    u16* dst = att + (size_t)nodei*512 + nh2*16;
    *(uint4*)dst       = make_uint4(p[0],p[1],p[2],p[3]);
    *(uint4*)(dst + 8) = make_uint4(p[4],p[5],p[6],p[7]);
  }
}

// =====================================================================
// K5 (MFMA): out0 = exp(log_scale) * (att @ w_post^T + b_post), K=512.
// Tile 128x64, wave tile 64x32 (acc 4x2), BK=32.
// =====================================================================
__global__ __launch_bounds__(256) void k_post(
    const u16* __restrict__ att, const float* __restrict__ wpost,
    const float* __restrict__ bpost, const float* __restrict__ ls,
    float* __restrict__ out0, int N, int nbm)
{
  __shared__ __align__(16) u16 As[128*40];
  __shared__ __align__(16) u16 Bs[64*40];
  const int t = threadIdx.x;
  const int bm = blockIdx.x % nbm;
  const int bn = blockIdx.x / nbm;          // 0..3
  const int m_base = bm*128, n_base = bn*64;
  const int w = t >> 6, lane = t & 63;
  const int wr = (w >> 1)*64, wc = (w & 1)*32;
  const int fr = lane & 15, fk = lane >> 4;
  const int arow = t >> 1, acol = (t & 1)*16;
  const int brow = t >> 2, bcol = (t & 3)*8;

  v4f acc[4][2];
#pragma unroll
  for (int i = 0; i < 4; i++)
#pragma unroll
    for (int j = 0; j < 2; j++) acc[i][j] = (v4f){0.f,0.f,0.f,0.f};

  for (int k0 = 0; k0 < 512; k0 += 32) {
    __syncthreads();
    {
      int gm = m_base + arow;
      uint4 a0 = make_uint4(0u,0u,0u,0u), a1 = make_uint4(0u,0u,0u,0u);
      if (gm < N) {
        a0 = *(const uint4*)(att + (size_t)gm*512 + k0 + acol);
        a1 = *(const uint4*)(att + (size_t)gm*512 + k0 + acol + 8);
      }
      *(uint4*)&As[arow*40 + acol]     = a0;
      *(uint4*)&As[arow*40 + acol + 8] = a1;
      uint4 bv = loadpack8(wpost + (size_t)(n_base + brow)*512 + k0 + bcol);
      *(uint4*)&Bs[brow*40 + bcol] = bv;
    }
    __syncthreads();
    v8s b0 = *(const v8s*)&Bs[(wc      + fr)*40 + fk*8];
    v8s b1 = *(const v8s*)&Bs[(wc + 16 + fr)*40 + fk*8];
#pragma unroll
    for (int mi = 0; mi < 4; mi++) {
      v8s a = *(const v8s*)&As[(wr + mi*16 + fr)*40 + fk*8];
      acc[mi][0] = __builtin_amdgcn_mfma_f32_16x16x32_bf16(a,b0,acc[mi][0],0,0,0);
      acc[mi][1] = __builtin_amdgcn_mfma_f32_16x16x32_bf16(a,b1,acc[mi][1],0,0,0);
    }
  }
#pragma unroll
  for (int nj = 0; nj < 2; nj++) {
    int col = n_base + wc + nj*16 + fr;
    float bpv = bpost[col];
    float e   = __expf(ls[col]);
#pragma unroll
    for (int mi = 0; mi < 4; mi++) {
#pragma unroll
      for (int r = 0; r < 4; r++) {
        int row = m_base + wr + mi*16 + fk*4 + r;
        if (row < N) out0[(size_t)row*256 + col] = e*(acc[mi][nj][r] + bpv);
      }
    }
  }
}

// =====================================================================
extern "C" void kernel_launch(void* const* d_in, const int* in_sizes, int n_in,
                              void* d_out, int out_size, void* d_ws, size_t ws_size,
                              hipStream_t stream)
{
  const float* x     = (const float*)d_in[0];
  const float* xres  = (const float*)d_in[1];
  const int*   batch = (const int*)d_in[2];
  const float* wpre  = (const float*)d_in[4];
  const float* bpre  = (const float*)d_in[5];
  const float* wq    = (const float*)d_in[6];
  const float* wk    = (const float*)d_in[7];
  const float* wv    = (const float*)d_in[8];
  const float* wpost = (const float*)d_in[9];
  const float* bpost = (const float*)d_in[10];
  const float* ls    = (const float*)d_in[11];

  const int N = in_sizes[0] / 256;     // 20000 nodes
  const int B = in_sizes[1] / 8192;    // 1024 graphs
  const int nbm = (N + 127) / 128;     // 157 row tiles (128-node)
  const int nchunk = (N + 255) / 256;  // 79 node chunks

  char* ws = (char*)d_ws;
  size_t off = 0;
  int*   flags  = (int*)(ws + off); off += 256;
  int*   bounds = (int*)(ws + off); off += ((size_t)B + 64) * 4;
  float* y      = (float*)(ws + off);                          // reused for att
  u16*   att    = (u16*)(ws + off);  off += (size_t)N * 1024;
  u16*   q      = (u16*)(ws + off);  off += (size_t)N * 1024;
  u16*   kten   = (u16*)(ws + off);  off += (size_t)N * 1024;
  u16*   vten   = (u16*)(ws + off);  off += (size_t)N * 1024;

  float* out0 = (float*)d_out;
  float* out1 = out0 + (size_t)N * 256;

  hipMemsetAsync(flags, 0, 4, stream);
  k_detect<<<nchunk,         256, 0, stream>>>(batch, N, flags);
  k_bounds<<<nchunk,         256, 0, stream>>>(batch, flags, N, B, bounds);
  k_pre   <<<nbm * 4,        256, 0, stream>>>(x, wpre, bpre, y, N, nbm);
  k_gnqkv <<<nchunk * 16,    256, 0, stream>>>(y, wq, wk, wv, q, kten, vten, N);
  k_segatt<<<B,              512, 0, stream>>>(kten, vten, q, xres, bounds,
                                               out1, att, N);
  k_post  <<<nbm * 4,        256, 0, stream>>>(att, wpost, bpost, ls, out0, N, nbm);
}

// Round 14
// 136.249 us; speedup vs baseline: 1.2801x; 1.0045x over previous
//
#include <hip/hip_runtime.h>
#include <stdint.h>

typedef unsigned int u32;
typedef unsigned short u16;
typedef __attribute__((ext_vector_type(8))) short v8s;   // 8 bf16 (4 VGPRs)
typedef __attribute__((ext_vector_type(4))) float v4f;   // 4 f32 acc

#define GN_EPS 1e-5f

union U4V8 { uint4 u; v8s s; };

// ---------- bf16 helpers (intermediates in ws are bf16) ----------
__device__ __forceinline__ float bflo(u32 u){ return __uint_as_float(u << 16); }
__device__ __forceinline__ float bfhi(u32 u){ return __uint_as_float(u & 0xffff0000u); }
__device__ __forceinline__ u16 f2bf(float f){
  u32 x = __float_as_uint(f);
  u32 r = (x + 0x7fffu + ((x >> 16) & 1u)) >> 16;   // RNE
  return (u16)r;
}
__device__ __forceinline__ u32 pack2(float a, float b){
  return (u32)f2bf(a) | ((u32)f2bf(b) << 16);
}
__device__ __forceinline__ void unpack8(const uint4 u, float* f){
  f[0]=bflo(u.x); f[1]=bfhi(u.x); f[2]=bflo(u.y); f[3]=bfhi(u.y);
  f[4]=bflo(u.z); f[5]=bfhi(u.z); f[6]=bflo(u.w); f[7]=bfhi(u.w);
}
// load 8 f32, return packed bf16 (4 u32)
__device__ __forceinline__ uint4 loadpack8(const float* __restrict__ p){
  float4 a = *(const float4*)p, b = *(const float4*)(p + 4);
  return make_uint4(pack2(a.x,a.y),pack2(a.z,a.w),pack2(b.x,b.y),pack2(b.z,b.w));
}

// batch accessor: int32 or int64 (little-endian low word)
__device__ __forceinline__ int getb(const int* __restrict__ b, int is64, int i){
  return b[is64 ? 2*i : i];
}

// =====================================================================
// K0: detect batch int-width (parallel).
// =====================================================================
__global__ __launch_bounds__(256) void k_detect(
    const int* __restrict__ batch, int n, int* __restrict__ flags)
{
  int i = blockIdx.x*256 + threadIdx.x;
  int bad = 0;
  if (i < n - 1 && batch[i] > batch[i + 1]) bad = 1;
  if (__builtin_amdgcn_ballot_w64(bad) != 0 && (threadIdx.x & 63) == 0)
    atomicOr(&flags[0], 1);
}

// =====================================================================
// K0b: CSR bounds. bounds[g] = first node of graph g; bounds[B] = N.
// =====================================================================
__global__ __launch_bounds__(256) void k_bounds(
    const int* __restrict__ batch, const int* __restrict__ flags,
    int N, int B, int* __restrict__ bounds)
{
  int i = blockIdx.x*256 + threadIdx.x;
  if (i >= N) return;
  const int is64 = flags[0];
  int b = getb(batch, is64, i);
  int prev = (i == 0) ? -1 : getb(batch, is64, i - 1);
  for (int g = prev + 1; g <= b; g++) bounds[g] = i;
  if (i == N - 1)
    for (int g = b + 1; g <= B; g++) bounds[g] = N;
}

// =====================================================================
// K1 (MFMA): y = x @ w_pre^T + b_pre, f32 out. Tile 128x64.
// =====================================================================
__global__ __launch_bounds__(256) void k_pre(
    const float* __restrict__ x, const float* __restrict__ wpre,
    const float* __restrict__ bpre, float* __restrict__ y, int N, int nbm)
{
  __shared__ __align__(16) u16 As[128*40];
  __shared__ __align__(16) u16 Bs[64*40];
  const int t = threadIdx.x;
  const int bm = blockIdx.x % nbm;
  const int bn = blockIdx.x / nbm;          // 0..3
  const int m_base = bm*128, n_base = bn*64;
  const int w = t >> 6, lane = t & 63;
  const int wr = (w >> 1)*64, wc = (w & 1)*32;
  const int fr = lane & 15, fk = lane >> 4;
  const int arow = t >> 1, acol = (t & 1)*16;
  const int brow = t >> 2, bcol = (t & 3)*8;

  v4f acc[4][2];
#pragma unroll
  for (int i = 0; i < 4; i++)
#pragma unroll
    for (int j = 0; j < 2; j++) acc[i][j] = (v4f){0.f,0.f,0.f,0.f};

  for (int k0 = 0; k0 < 256; k0 += 32) {
    __syncthreads();
    {
      int gm = m_base + arow;
      uint4 a0 = make_uint4(0u,0u,0u,0u), a1 = make_uint4(0u,0u,0u,0u);
      if (gm < N) {
        a0 = loadpack8(x + (size_t)gm*256 + k0 + acol);
        a1 = loadpack8(x + (size_t)gm*256 + k0 + acol + 8);
      }
      *(uint4*)&As[arow*40 + acol]     = a0;
      *(uint4*)&As[arow*40 + acol + 8] = a1;
      uint4 bv = loadpack8(wpre + (size_t)(n_base + brow)*256 + k0 + bcol);
      *(uint4*)&Bs[brow*40 + bcol] = bv;
    }
    __syncthreads();
    v8s b0 = *(const v8s*)&Bs[(wc      + fr)*40 + fk*8];
    v8s b1 = *(const v8s*)&Bs[(wc + 16 + fr)*40 + fk*8];
#pragma unroll
    for (int mi = 0; mi < 4; mi++) {
      v8s a = *(const v8s*)&As[(wr + mi*16 + fr)*40 + fk*8];
      acc[mi][0] = __builtin_amdgcn_mfma_f32_16x16x32_bf16(a,b0,acc[mi][0],0,0,0);
      acc[mi][1] = __builtin_amdgcn_mfma_f32_16x16x32_bf16(a,b1,acc[mi][1],0,0,0);
    }
  }
#pragma unroll
  for (int nj = 0; nj < 2; nj++) {
    int col = n_base + wc + nj*16 + fr;
    float bpv = bpre[col];
#pragma unroll
    for (int mi = 0; mi < 4; mi++) {
#pragma unroll
      for (int r = 0; r < 4; r++) {
        int row = m_base + wr + mi*16 + fk*4 + r;
        if (row < N) y[(size_t)row*256 + col] = acc[mi][nj][r] + bpv;
      }
    }
  }
}

// =====================================================================
// K2: GroupNorm + grouped q/k/v. q node-major; k,v transposed to
// kT/vT[(head*16+dim)*Npad + node] (coalesced scalar stores).
// =====================================================================
__device__ __forceinline__ float dot16(const float* __restrict__ yn,
                                       const float* __restrict__ row){
  float4 W0 = *(const float4*)row;
  float4 W1 = *(const float4*)(row + 4);
  float4 W2 = *(const float4*)(row + 8);
  float4 W3 = *(const float4*)(row + 12);
  float d = 0.f;
  d = fmaf(yn[0],W0.x,d); d = fmaf(yn[1],W0.y,d);
  d = fmaf(yn[2],W0.z,d); d = fmaf(yn[3],W0.w,d);
  d = fmaf(yn[4],W1.x,d); d = fmaf(yn[5],W1.y,d);
  d = fmaf(yn[6],W1.z,d); d = fmaf(yn[7],W1.w,d);
  d = fmaf(yn[8],W2.x,d); d = fmaf(yn[9],W2.y,d);
  d = fmaf(yn[10],W2.z,d); d = fmaf(yn[11],W2.w,d);
  d = fmaf(yn[12],W3.x,d); d = fmaf(yn[13],W3.y,d);
  d = fmaf(yn[14],W3.z,d); d = fmaf(yn[15],W3.w,d);
  return d;
}

__global__ __launch_bounds__(256) void k_gnqkv(
    const float* __restrict__ y, const float* __restrict__ wq,
    const float* __restrict__ wk, const float* __restrict__ wv,
    u16* __restrict__ qo, u16* __restrict__ kT, u16* __restrict__ vT,
    int N, int Npad)
{
  __shared__ __align__(16) float wL[3*512];
  const int t = threadIdx.x;
  const int g = blockIdx.x & 15;
  const int c = blockIdx.x >> 4;
  {
    const float* srcs[3] = {wq, wk, wv};
#pragma unroll
    for (int tz = 0; tz < 3; tz++) {
      wL[tz*512 + t]       = srcs[tz][g*512 + t];
      wL[tz*512 + t + 256] = srcs[tz][g*512 + t + 256];
    }
  }
  __syncthreads();
  const int node = c*256 + t;
  if (node >= N) return;

  const float* yp = y + (size_t)node*256 + g*16;
  float4 v0 = *(const float4*)yp;
  float4 v1 = *(const float4*)(yp + 4);
  float4 v2 = *(const float4*)(yp + 8);
  float4 v3 = *(const float4*)(yp + 12);
  float a[16] = {v0.x,v0.y,v0.z,v0.w, v1.x,v1.y,v1.z,v1.w,
                 v2.x,v2.y,v2.z,v2.w, v3.x,v3.y,v3.z,v3.w};
  float mu = 0.f;
#pragma unroll
  for (int i = 0; i < 16; i++) mu += a[i];
  mu *= 0.0625f;
  float s2 = 0.f;
#pragma unroll
  for (int i = 0; i < 16; i++) { float d = a[i]-mu; s2 = fmaf(d,d,s2); }
  float inv = rsqrtf(s2*0.0625f + GN_EPS);
  float yn[16];
#pragma unroll
  for (int i = 0; i < 16; i++) yn[i] = (a[i]-mu)*inv;

  // q: node-major packed
#pragma unroll
  for (int s = 0; s < 2; s++) {
    u32 p[8];
#pragma unroll
    for (int o = 0; o < 16; o++) {
      float d = __expf(dot16(yn, &wL[(s*16 + o)*16]) * 0.25f);
      if (o & 1) p[o>>1] |= (u32)f2bf(d) << 16;
      else       p[o>>1]  = (u32)f2bf(d);
    }
    u16* dst = qo + (size_t)node*512 + g*32 + s*16;
    *(uint4*)dst       = make_uint4(p[0],p[1],p[2],p[3]);
    *(uint4*)(dst + 8) = make_uint4(p[4],p[5],p[6],p[7]);
  }
  // k -> kT transposed
#pragma unroll
  for (int s = 0; s < 2; s++) {
#pragma unroll
    for (int o = 0; o < 16; o++) {
      float d = __expf(dot16(yn, &wL[512 + (s*16 + o)*16]) * 0.25f);
      kT[(size_t)((g*2 + s)*16 + o)*Npad + node] = f2bf(d);
    }
  }
  // v -> vT transposed (no exp, no scale)
#pragma unroll
  for (int s = 0; s < 2; s++) {
#pragma unroll
    for (int o = 0; o < 16; o++) {
      float d = dot16(yn, &wL[1024 + (s*16 + o)*16]);
      vT[(size_t)((g*2 + s)*16 + o)*Npad + node] = f2bf(d);
    }
  }
}

// =====================================================================
// K3 (fused, MFMA phase-1): 512 threads, 8 waves x 4 heads.
// Phase 1: per 32-aligned node chunk, per head:
//   KV[d][e] += sum_n kT[d][n]*vT[e][n]  (1 MFMA)
//   ks[d]    += sum_n kT[d][n]*ones[n]   (1 MFMA)
//   both fragments AND-masked to [lo,hi) (kills garbage incl. NaN).
// Phase 2: out1 = KV + xres (f32, from acc regs); kv -> LDS bf16
//   (head stride 280), ks -> LDS.
// Phase 3: att from LDS (round-8 code).
// =====================================================================
__global__ __launch_bounds__(512) void k_segatt(
    const u16* __restrict__ kT, const u16* __restrict__ vT,
    const u16* __restrict__ xq, const float* __restrict__ xres,
    const int* __restrict__ bounds,
    float* __restrict__ out1, u16* __restrict__ att, int N, int Npad)
{
  __shared__ __align__(16) u16 kvs[32*280];     // 17.5 KB
  __shared__ float kss[32*17];                  // 2.2 KB
  const int b = blockIdx.x, t = threadIdx.x;
  const int lo = bounds[b], hi = bounds[b+1];
  const int w = t >> 6, lane = t & 63;
  const int fr = lane & 15, fk = lane >> 4;

  v4f akv[4], aks[4];
#pragma unroll
  for (int hh = 0; hh < 4; hh++) {
    akv[hh] = (v4f){0.f,0.f,0.f,0.f};
    aks[hh] = (v4f){0.f,0.f,0.f,0.f};
  }

  // ---- phase 1: MFMA over 32-aligned node chunks ----
  for (int n0 = (lo & ~31); n0 < hi; n0 += 32) {
    const int nbase = n0 + fk*8;
    u32 msk[4];
#pragma unroll
    for (int m = 0; m < 4; m++) {
      int na = nbase + 2*m, nb = na + 1;
      u32 mm = 0u;
      if (na >= lo && na < hi) mm |= 0x0000FFFFu;
      if (nb >= lo && nb < hi) mm |= 0xFFFF0000u;
      msk[m] = mm;
    }
    U4V8 onesu;
    onesu.u = make_uint4(msk[0] & 0x3F803F80u, msk[1] & 0x3F803F80u,
                         msk[2] & 0x3F803F80u, msk[3] & 0x3F803F80u);
#pragma unroll
    for (int hh = 0; hh < 4; hh++) {
      const int head = w*4 + hh;
      U4V8 ku, vu;
      ku.u = *(const uint4*)(kT + (size_t)(head*16 + fr)*Npad + nbase);
      vu.u = *(const uint4*)(vT + (size_t)(head*16 + fr)*Npad + nbase);
      ku.u.x &= msk[0]; ku.u.y &= msk[1]; ku.u.z &= msk[2]; ku.u.w &= msk[3];
      vu.u.x &= msk[0]; vu.u.y &= msk[1]; vu.u.z &= msk[2]; vu.u.w &= msk[3];
      akv[hh] = __builtin_amdgcn_mfma_f32_16x16x32_bf16(ku.s, vu.s, akv[hh],0,0,0);
      aks[hh] = __builtin_amdgcn_mfma_f32_16x16x32_bf16(ku.s, onesu.s, aks[hh],0,0,0);
    }
  }

  // ---- phase 2: out1 = KV + xres; kv/ks -> LDS ----
#pragma unroll
  for (int hh = 0; hh < 4; hh++) {
    const int head = w*4 + hh;
    const size_t hbase = ((size_t)b*32 + head)*256;
#pragma unroll
    for (int r = 0; r < 4; r++) {
      int d = fk*4 + r;
      size_t idx = hbase + d*16 + fr;
      float o = akv[hh][r] + xres[idx];
      out1[idx] = o;
      kvs[head*280 + d*16 + fr] = f2bf(o);
    }
    if (fr == 0) {
#pragma unroll
      for (int r = 0; r < 4; r++)
        kss[head*17 + fk*4 + r] = aks[hh][r];
    }
  }
  __syncthreads();

  // ---- phase 3: att, 16 node-slots per iter ----
  const int nh2 = t & 31, ns = t >> 5;   // ns 0..15
  for (int n0 = lo; n0 < hi; n0 += 16) {
    int nodei = n0 + ns;
    if (nodei >= hi) continue;
    const u16* qp = xq + (size_t)nodei*512 + nh2*16;
    uint4 Q0 = *(const uint4*)qp;
    uint4 Q1 = *(const uint4*)(qp + 8);
    float q[16]; unpack8(Q0, q); unpack8(Q1, q + 8);
    const float* ksp = &kss[nh2*17];
    float denom = 0.f;
#pragma unroll
    for (int i = 0; i < 16; i++) denom = fmaf(q[i], ksp[i], denom);
    float inv = 1.0f / fmaxf(denom, 1e-20f);
    float a[16];
#pragma unroll
    for (int v = 0; v < 16; v++) a[v] = 0.f;
    const u16* kvp = &kvs[nh2*280];
#pragma unroll
    for (int h = 0; h < 16; h++) {
      float qh = q[h] * inv;
      uint4 W0 = *(const uint4*)(kvp + h*16);
      uint4 W1 = *(const uint4*)(kvp + h*16 + 8);
      float wv[16]; unpack8(W0, wv); unpack8(W1, wv + 8);
#pragma unroll
      for (int v = 0; v < 16; v++) a[v] = fmaf(qh, wv[v], a[v]);
    }
    u32 p[8];
#pragma unroll
    for (int j = 0; j < 8; j++) p[j] = pack2(a[2*j], a[2*j+1]);
    u16* dst = att + (size_t)nodei*512 + nh2*16;
    *(uint4*)dst       = make_uint4(p[0],p[1],p[2],p[3]);
    *(uint4*)(dst + 8) = make_uint4(p[4],p[5],p[6],p[7]);
  }
}

// =====================================================================
// K5 (MFMA): out0 = exp(log_scale) * (att @ w_post^T + b_post), K=512.
// Tile 128x64.
// =====================================================================
__global__ __launch_bounds__(256) void k_post(
    const u16* __restrict__ att, const float* __restrict__ wpost,
    const float* __restrict__ bpost, const float* __restrict__ ls,
    float* __restrict__ out0, int N, int nbm)
{
  __shared__ __align__(16) u16 As[128*40];
  __shared__ __align__(16) u16 Bs[64*40];
  const int t = threadIdx.x;
  const int bm = blockIdx.x % nbm;
  const int bn = blockIdx.x / nbm;          // 0..3
  const int m_base = bm*128, n_base = bn*64;
  const int w = t >> 6, lane = t & 63;
  const int wr = (w >> 1)*64, wc = (w & 1)*32;
  const int fr = lane & 15, fk = lane >> 4;
  const int arow = t >> 1, acol = (t & 1)*16;
  const int brow = t >> 2, bcol = (t & 3)*8;

  v4f acc[4][2];
#pragma unroll
  for (int i = 0; i < 4; i++)
#pragma unroll
    for (int j = 0; j < 2; j++) acc[i][j] = (v4f){0.f,0.f,0.f,0.f};

  for (int k0 = 0; k0 < 512; k0 += 32) {
    __syncthreads();
    {
      int gm = m_base + arow;
      uint4 a0 = make_uint4(0u,0u,0u,0u), a1 = make_uint4(0u,0u,0u,0u);
      if (gm < N) {
        a0 = *(const uint4*)(att + (size_t)gm*512 + k0 + acol);
        a1 = *(const uint4*)(att + (size_t)gm*512 + k0 + acol + 8);
      }
      *(uint4*)&As[arow*40 + acol]     = a0;
      *(uint4*)&As[arow*40 + acol + 8] = a1;
      uint4 bv = loadpack8(wpost + (size_t)(n_base + brow)*512 + k0 + bcol);
      *(uint4*)&Bs[brow*40 + bcol] = bv;
    }
    __syncthreads();
    v8s b0 = *(const v8s*)&Bs[(wc      + fr)*40 + fk*8];
    v8s b1 = *(const v8s*)&Bs[(wc + 16 + fr)*40 + fk*8];
#pragma unroll
    for (int mi = 0; mi < 4; mi++) {
      v8s a = *(const v8s*)&As[(wr + mi*16 + fr)*40 + fk*8];
      acc[mi][0] = __builtin_amdgcn_mfma_f32_16x16x32_bf16(a,b0,acc[mi][0],0,0,0);
      acc[mi][1] = __builtin_amdgcn_mfma_f32_16x16x32_bf16(a,b1,acc[mi][1],0,0,0);
    }
  }
#pragma unroll
  for (int nj = 0; nj < 2; nj++) {
    int col = n_base + wc + nj*16 + fr;
    float bpv = bpost[col];
    float e   = __expf(ls[col]);
#pragma unroll
    for (int mi = 0; mi < 4; mi++) {
#pragma unroll
      for (int r = 0; r < 4; r++) {
        int row = m_base + wr + mi*16 + fk*4 + r;
        if (row < N) out0[(size_t)row*256 + col] = e*(acc[mi][nj][r] + bpv);
      }
    }
  }
}

// =====================================================================
extern "C" void kernel_launch(void* const* d_in, const int* in_sizes, int n_in,
                              void* d_out, int out_size, void* d_ws, size_t ws_size,
                              hipStream_t stream)
{
  const float* x     = (const float*)d_in[0];
  const float* xres  = (const float*)d_in[1];
  const int*   batch = (const int*)d_in[2];
  const float* wpre  = (const float*)d_in[4];
  const float* bpre  = (const float*)d_in[5];
  const float* wq    = (const float*)d_in[6];
  const float* wk    = (const float*)d_in[7];
  const float* wv    = (const float*)d_in[8];
  const float* wpost = (const float*)d_in[9];
  const float* bpost = (const float*)d_in[10];
  const float* ls    = (const float*)d_in[11];

  const int N = in_sizes[0] / 256;     // 20000 nodes
  const int B = in_sizes[1] / 8192;    // 1024 graphs
  const int nbm = (N + 127) / 128;     // 157 row tiles
  const int nchunk = (N + 255) / 256;  // 79 node chunks
  const int Npad = ((N + 64 + 7) / 8) * 8;   // 16B-aligned transposed rows

  char* ws = (char*)d_ws;
  size_t off = 0;
  int*   flags  = (int*)(ws + off); off += 256;
  int*   bounds = (int*)(ws + off); off += ((size_t)B + 64) * 4;
  float* y      = (float*)(ws + off);                          // reused for att
  u16*   att    = (u16*)(ws + off);  off += (size_t)N * 1024;
  u16*   q      = (u16*)(ws + off);  off += (size_t)N * 1024;
  u16*   kT     = (u16*)(ws + off);  off += (size_t)512 * Npad * 2;
  u16*   vT     = (u16*)(ws + off);  off += (size_t)512 * Npad * 2;

  float* out0 = (float*)d_out;
  float* out1 = out0 + (size_t)N * 256;

  hipMemsetAsync(flags, 0, 4, stream);
  k_detect<<<nchunk,         256, 0, stream>>>(batch, N, flags);
  k_bounds<<<nchunk,         256, 0, stream>>>(batch, flags, N, B, bounds);
  k_pre   <<<nbm * 4,        256, 0, stream>>>(x, wpre, bpre, y, N, nbm);
  k_gnqkv <<<nchunk * 16,    256, 0, stream>>>(y, wq, wk, wv, q, kT, vT, N, Npad);
  k_segatt<<<B,              512, 0, stream>>>(kT, vT, q, xres, bounds,
                                               out1, att, N, Npad);
  k_post  <<<nbm * 4,        256, 0, stream>>>(att, wpost, bpost, ls, out0, N, nbm);
}

// Round 15
// 133.109 us; speedup vs baseline: 1.3103x; 1.0236x over previous
//
#include <hip/hip_runtime.h>
#include <stdint.h>

typedef unsigned int u32;
typedef unsigned short u16;
typedef __attribute__((ext_vector_type(8))) short v8s;   // 8 bf16 (4 VGPRs)
typedef __attribute__((ext_vector_type(4))) float v4f;   // 4 f32 acc

#define GN_EPS 1e-5f

// ---------- bf16 helpers (intermediates in ws are bf16) ----------
__device__ __forceinline__ float bflo(u32 u){ return __uint_as_float(u << 16); }
__device__ __forceinline__ float bfhi(u32 u){ return __uint_as_float(u & 0xffff0000u); }
__device__ __forceinline__ u16 f2bf(float f){
  u32 x = __float_as_uint(f);
  u32 r = (x + 0x7fffu + ((x >> 16) & 1u)) >> 16;   // RNE
  return (u16)r;
}
__device__ __forceinline__ u32 pack2(float a, float b){
  return (u32)f2bf(a) | ((u32)f2bf(b) << 16);
}
__device__ __forceinline__ void unpack8(const uint4 u, float* f){
  f[0]=bflo(u.x); f[1]=bfhi(u.x); f[2]=bflo(u.y); f[3]=bfhi(u.y);
  f[4]=bflo(u.z); f[5]=bfhi(u.z); f[6]=bflo(u.w); f[7]=bfhi(u.w);
}
// load 8 f32, return packed bf16 (4 u32)
__device__ __forceinline__ uint4 loadpack8(const float* __restrict__ p){
  float4 a = *(const float4*)p, b = *(const float4*)(p + 4);
  return make_uint4(pack2(a.x,a.y),pack2(a.z,a.w),pack2(b.x,b.y),pack2(b.z,b.w));
}

// batch accessor: int32 or int64 (little-endian low word)
__device__ __forceinline__ int getb(const int* __restrict__ b, int is64, int i){
  return b[is64 ? 2*i : i];
}

// =====================================================================
// K0: detect batch int-width (parallel).
// =====================================================================
__global__ __launch_bounds__(256) void k_detect(
    const int* __restrict__ batch, int n, int* __restrict__ flags)
{
  int i = blockIdx.x*256 + threadIdx.x;
  int bad = 0;
  if (i < n - 1 && batch[i] > batch[i + 1]) bad = 1;
  if (__builtin_amdgcn_ballot_w64(bad) != 0 && (threadIdx.x & 63) == 0)
    atomicOr(&flags[0], 1);
}

// =====================================================================
// K0b: CSR bounds. bounds[g] = first node of graph g; bounds[B] = N.
// =====================================================================
__global__ __launch_bounds__(256) void k_bounds(
    const int* __restrict__ batch, const int* __restrict__ flags,
    int N, int B, int* __restrict__ bounds)
{
  int i = blockIdx.x*256 + threadIdx.x;
  if (i >= N) return;
  const int is64 = flags[0];
  int b = getb(batch, is64, i);
  int prev = (i == 0) ? -1 : getb(batch, is64, i - 1);
  for (int g = prev + 1; g <= b; g++) bounds[g] = i;
  if (i == N - 1)
    for (int g = b + 1; g <= B; g++) bounds[g] = N;
}

// =====================================================================
// K1 (MFMA): y = x @ w_pre^T + b_pre, bf16 out. Tile 128x64.
// =====================================================================
__global__ __launch_bounds__(256) void k_pre(
    const float* __restrict__ x, const float* __restrict__ wpre,
    const float* __restrict__ bpre, u16* __restrict__ y, int N, int nbm)
{
  __shared__ __align__(16) u16 As[128*40];
  __shared__ __align__(16) u16 Bs[64*40];
  const int t = threadIdx.x;
  const int bm = blockIdx.x % nbm;
  const int bn = blockIdx.x / nbm;          // 0..3
  const int m_base = bm*128, n_base = bn*64;
  const int w = t >> 6, lane = t & 63;
  const int wr = (w >> 1)*64, wc = (w & 1)*32;
  const int fr = lane & 15, fk = lane >> 4;
  const int arow = t >> 1, acol = (t & 1)*16;
  const int brow = t >> 2, bcol = (t & 3)*8;

  v4f acc[4][2];
#pragma unroll
  for (int i = 0; i < 4; i++)
#pragma unroll
    for (int j = 0; j < 2; j++) acc[i][j] = (v4f){0.f,0.f,0.f,0.f};

  for (int k0 = 0; k0 < 256; k0 += 32) {
    __syncthreads();
    {
      int gm = m_base + arow;
      uint4 a0 = make_uint4(0u,0u,0u,0u), a1 = make_uint4(0u,0u,0u,0u);
      if (gm < N) {
        a0 = loadpack8(x + (size_t)gm*256 + k0 + acol);
        a1 = loadpack8(x + (size_t)gm*256 + k0 + acol + 8);
      }
      *(uint4*)&As[arow*40 + acol]     = a0;
      *(uint4*)&As[arow*40 + acol + 8] = a1;
      uint4 bv = loadpack8(wpre + (size_t)(n_base + brow)*256 + k0 + bcol);
      *(uint4*)&Bs[brow*40 + bcol] = bv;
    }
    __syncthreads();
    v8s b0 = *(const v8s*)&Bs[(wc      + fr)*40 + fk*8];
    v8s b1 = *(const v8s*)&Bs[(wc + 16 + fr)*40 + fk*8];
#pragma unroll
    for (int mi = 0; mi < 4; mi++) {
      v8s a = *(const v8s*)&As[(wr + mi*16 + fr)*40 + fk*8];
      acc[mi][0] = __builtin_amdgcn_mfma_f32_16x16x32_bf16(a,b0,acc[mi][0],0,0,0);
      acc[mi][1] = __builtin_amdgcn_mfma_f32_16x16x32_bf16(a,b1,acc[mi][1],0,0,0);
    }
  }
#pragma unroll
  for (int nj = 0; nj < 2; nj++) {
    int col = n_base + wc + nj*16 + fr;
    float bpv = bpre[col];
#pragma unroll
    for (int mi = 0; mi < 4; mi++) {
#pragma unroll
      for (int r = 0; r < 4; r++) {
        int row = m_base + wr + mi*16 + fk*4 + r;
        if (row < N) y[(size_t)row*256 + col] = f2bf(acc[mi][nj][r] + bpv);
      }
    }
  }
}

// =====================================================================
// K2: block = (group g, 256-node chunk). Reads y bf16; GN in f32.
// =====================================================================
__global__ __launch_bounds__(256) void k_gnqkv(
    const u16* __restrict__ y, const float* __restrict__ wq,
    const float* __restrict__ wk, const float* __restrict__ wv,
    u16* __restrict__ qo, u16* __restrict__ ko, u16* __restrict__ vo, int N)
{
  __shared__ __align__(16) float wL[3*512];
  const int t = threadIdx.x;
  const int g = blockIdx.x & 15;
  const int c = blockIdx.x >> 4;
  {
    const float* srcs[3] = {wq, wk, wv};
#pragma unroll
    for (int tz = 0; tz < 3; tz++) {
      wL[tz*512 + t]       = srcs[tz][g*512 + t];
      wL[tz*512 + t + 256] = srcs[tz][g*512 + t + 256];
    }
  }
  __syncthreads();
  const int node = c*256 + t;
  if (node >= N) return;

  const u16* yp = y + (size_t)node*256 + g*16;
  uint4 Y0 = *(const uint4*)yp;
  uint4 Y1 = *(const uint4*)(yp + 8);
  float a[16]; unpack8(Y0, a); unpack8(Y1, a + 8);
  float mu = 0.f;
#pragma unroll
  for (int i = 0; i < 16; i++) mu += a[i];
  mu *= 0.0625f;
  float s2 = 0.f;
#pragma unroll
  for (int i = 0; i < 16; i++) { float d = a[i]-mu; s2 = fmaf(d,d,s2); }
  float inv = rsqrtf(s2*0.0625f + GN_EPS);
  float yn[16];
#pragma unroll
  for (int i = 0; i < 16; i++) yn[i] = (a[i]-mu)*inv;

  u16* outs[3] = {qo, ko, vo};
#pragma unroll
  for (int tz = 0; tz < 3; tz++) {
#pragma unroll
    for (int s = 0; s < 2; s++) {
      u32 p[8];
#pragma unroll
      for (int o = 0; o < 16; o++) {
        const float* row = &wL[tz*512 + (s*16 + o)*16];
        float4 W0 = *(const float4*)row;
        float4 W1 = *(const float4*)(row + 4);
        float4 W2 = *(const float4*)(row + 8);
        float4 W3 = *(const float4*)(row + 12);
        float w[16] = {W0.x,W0.y,W0.z,W0.w,W1.x,W1.y,W1.z,W1.w,
                       W2.x,W2.y,W2.z,W2.w,W3.x,W3.y,W3.z,W3.w};
        float d = 0.f;
#pragma unroll
        for (int i = 0; i < 16; i++) d = fmaf(yn[i], w[i], d);
        if (tz < 2) d = __expf(d*0.25f);
        if (o & 1) p[o>>1] |= (u32)f2bf(d) << 16;
        else       p[o>>1]  = (u32)f2bf(d);
      }
      u16* dst = outs[tz] + (size_t)node*512 + g*32 + s*16;
      *(uint4*)dst       = make_uint4(p[0],p[1],p[2],p[3]);
      *(uint4*)(dst + 8) = make_uint4(p[4],p[5],p[6],p[7]);
    }
  }
}

// =====================================================================
// K3 (512 threads, fused — round-8/13 version): per-graph segment-sum
// + att. Phase 1 two node-halves; reduce via LDS; phase 2 out1+LDS kv;
// phase 3 att from LDS-resident kv.
// =====================================================================
__global__ __launch_bounds__(512) void k_segatt(
    const u16* __restrict__ xk, const u16* __restrict__ xv,
    const u16* __restrict__ xq, const float* __restrict__ xres,
    const int* __restrict__ bounds,
    float* __restrict__ out1, u16* __restrict__ att, int N)
{
  __shared__ __align__(16) float red[512*20];   // 40 KB
  __shared__ __align__(16) float kspart[512];   // 2 KB
  __shared__ __align__(16) u16 kvs[32*280];     // 17.5 KB
  __shared__ float kss[32*17];                  // 2.2 KB
  const int b = blockIdx.x, t = threadIdx.x;
  const int lo = bounds[b], hi = bounds[b+1];
  const int half = t >> 8;
  const int nh = (t >> 3) & 31, hp = t & 7;

  float kv[2][16];
#pragma unroll
  for (int r = 0; r < 2; r++)
#pragma unroll
    for (int v = 0; v < 16; v++) kv[r][v] = 0.f;
  float ks0 = 0.f, ks1 = 0.f;

  // ---- phase 1: direct-from-global, interleaved halves, unroll x2 ----
  const size_t koff = (size_t)nh*16 + 2*hp;
  const size_t voff = (size_t)nh*16;
  int node = lo + half;
  for (; node + 2 < hi; node += 4) {
    u32  kw0 = *(const u32*) (xk + (size_t)node*512 + koff);
    uint4 Va0 = *(const uint4*)(xv + (size_t)node*512 + voff);
    uint4 Va1 = *(const uint4*)(xv + (size_t)node*512 + voff + 8);
    u32  kw1 = *(const u32*) (xk + (size_t)(node+2)*512 + koff);
    uint4 Vb0 = *(const uint4*)(xv + (size_t)(node+2)*512 + voff);
    uint4 Vb1 = *(const uint4*)(xv + (size_t)(node+2)*512 + voff + 8);
    float a0 = bflo(kw0), a1 = bfhi(kw0);
    float b0 = bflo(kw1), b1 = bfhi(kw1);
    float va[16], vb[16];
    unpack8(Va0, va); unpack8(Va1, va + 8);
    unpack8(Vb0, vb); unpack8(Vb1, vb + 8);
    ks0 += a0 + b0; ks1 += a1 + b1;
#pragma unroll
    for (int v = 0; v < 16; v++) {
      kv[0][v] = fmaf(a0, va[v], kv[0][v]);
      kv[1][v] = fmaf(a1, va[v], kv[1][v]);
      kv[0][v] = fmaf(b0, vb[v], kv[0][v]);
      kv[1][v] = fmaf(b1, vb[v], kv[1][v]);
    }
  }
  if (node < hi) {
    u32  kw = *(const u32*) (xk + (size_t)node*512 + koff);
    uint4 V0 = *(const uint4*)(xv + (size_t)node*512 + voff);
    uint4 V1 = *(const uint4*)(xv + (size_t)node*512 + voff + 8);
    float k0 = bflo(kw), k1 = bfhi(kw);
    float vf[16]; unpack8(V0, vf); unpack8(V1, vf + 8);
    ks0 += k0; ks1 += k1;
#pragma unroll
    for (int v = 0; v < 16; v++) {
      kv[0][v] = fmaf(k0, vf[v], kv[0][v]);
      kv[1][v] = fmaf(k1, vf[v], kv[1][v]);
    }
  }

  // ---- reduce halves ----
  if (half == 0) {
#pragma unroll
    for (int r = 0; r < 2; r++) {
      float* rp = &red[(nh*16 + 2*hp + r)*20];
      *(float4*)rp       = make_float4(kv[r][0], kv[r][1], kv[r][2], kv[r][3]);
      *(float4*)(rp + 4) = make_float4(kv[r][4], kv[r][5], kv[r][6], kv[r][7]);
      *(float4*)(rp + 8) = make_float4(kv[r][8], kv[r][9], kv[r][10],kv[r][11]);
      *(float4*)(rp + 12)= make_float4(kv[r][12],kv[r][13],kv[r][14],kv[r][15]);
    }
    kspart[nh*16 + 2*hp]     = ks0;
    kspart[nh*16 + 2*hp + 1] = ks1;
  }
  __syncthreads();

  if (half == 1) {
#pragma unroll
    for (int r = 0; r < 2; r++) {
      const float* rp = &red[(nh*16 + 2*hp + r)*20];
      float4 R0 = *(const float4*)rp;
      float4 R1 = *(const float4*)(rp + 4);
      float4 R2 = *(const float4*)(rp + 8);
      float4 R3 = *(const float4*)(rp + 12);
      kv[r][0] += R0.x; kv[r][1] += R0.y; kv[r][2] += R0.z; kv[r][3] += R0.w;
      kv[r][4] += R1.x; kv[r][5] += R1.y; kv[r][6] += R1.z; kv[r][7] += R1.w;
      kv[r][8] += R2.x; kv[r][9] += R2.y; kv[r][10]+= R2.z; kv[r][11]+= R2.w;
      kv[r][12]+= R3.x; kv[r][13]+= R3.y; kv[r][14]+= R3.z; kv[r][15]+= R3.w;
    }
    ks0 += kspart[nh*16 + 2*hp];
    ks1 += kspart[nh*16 + 2*hp + 1];
    kss[nh*17 + 2*hp]     = ks0;
    kss[nh*17 + 2*hp + 1] = ks1;

    // ---- phase 2: out1 = kv + xres; kv -> LDS (bf16) ----
#pragma unroll
    for (int r = 0; r < 2; r++) {
      int h = 2*hp + r;
      size_t idx = ((size_t)(b*32 + nh)*16 + h)*16;
      const float* xp = xres + idx;
      float4 X0 = *(const float4*)xp;
      float4 X1 = *(const float4*)(xp + 4);
      float4 X2 = *(const float4*)(xp + 8);
      float4 X3 = *(const float4*)(xp + 12);
      float xf[16] = {X0.x,X0.y,X0.z,X0.w,X1.x,X1.y,X1.z,X1.w,
                      X2.x,X2.y,X2.z,X2.w,X3.x,X3.y,X3.z,X3.w};
      float o[16];
#pragma unroll
      for (int j = 0; j < 16; j++) o[j] = kv[r][j] + xf[j];
      float* op = out1 + idx;
      *(float4*)op        = make_float4(o[0],o[1],o[2],o[3]);
      *(float4*)(op + 4)  = make_float4(o[4],o[5],o[6],o[7]);
      *(float4*)(op + 8)  = make_float4(o[8],o[9],o[10],o[11]);
      *(float4*)(op + 12) = make_float4(o[12],o[13],o[14],o[15]);
      u16* lp = &kvs[nh*280 + h*16];
      *(uint4*)lp       = make_uint4(pack2(o[0],o[1]),  pack2(o[2],o[3]),
                                     pack2(o[4],o[5]),  pack2(o[6],o[7]));
      *(uint4*)(lp + 8) = make_uint4(pack2(o[8],o[9]),  pack2(o[10],o[11]),
                                     pack2(o[12],o[13]),pack2(o[14],o[15]));
    }
  }
  __syncthreads();

  // ---- phase 3: att, 16 node-slots per iter ----
  const int nh2 = t & 31, ns = t >> 5;   // ns 0..15
  for (int n0 = lo; n0 < hi; n0 += 16) {
    int nodei = n0 + ns;
    if (nodei >= hi) continue;
    const u16* qp = xq + (size_t)nodei*512 + nh2*16;
    uint4 Q0 = *(const uint4*)qp;
    uint4 Q1 = *(const uint4*)(qp + 8);
    float q[16]; unpack8(Q0, q); unpack8(Q1, q + 8);
    const float* ksp = &kss[nh2*17];
    float denom = 0.f;
#pragma unroll
    for (int i = 0; i < 16; i++) denom = fmaf(q[i], ksp[i], denom);
    float inv = 1.0f / fmaxf(denom, 1e-20f);
    float a[16];
#pragma unroll
    for (int v = 0; v < 16; v++) a[v] = 0.f;
    const u16* kvp = &kvs[nh2*280];
#pragma unroll
    for (int h = 0; h < 16; h++) {
      float qh = q[h] * inv;
      uint4 W0 = *(const uint4*)(kvp + h*16);
      uint4 W1 = *(const uint4*)(kvp + h*16 + 8);
      float w[16]; unpack8(W0, w); unpack8(W1, w + 8);
#pragma unroll
      for (int v = 0; v < 16; v++) a[v] = fmaf(qh, w[v], a[v]);
    }
    u32 p[8];
#pragma unroll
    for (int j = 0; j < 8; j++) p[j] = pack2(a[2*j], a[2*j+1]);
    u16* dst = att + (size_t)nodei*512 + nh2*16;
    *(uint4*)dst       = make_uint4(p[0],p[1],p[2],p[3]);
    *(uint4*)(dst + 8) = make_uint4(p[4],p[5],p[6],p[7]);
  }
}

// =====================================================================
// K5 (MFMA): out0 = exp(log_scale) * (att @ w_post^T + b_post), K=512.
// Tile 128x64.
// =====================================================================
__global__ __launch_bounds__(256) void k_post(
    const u16* __restrict__ att, const float* __restrict__ wpost,
    const float* __restrict__ bpost, const float* __restrict__ ls,
    float* __restrict__ out0, int N, int nbm)
{
  __shared__ __align__(16) u16 As[128*40];
  __shared__ __align__(16) u16 Bs[64*40];
  const int t = threadIdx.x;
  const int bm = blockIdx.x % nbm;
  const int bn = blockIdx.x / nbm;          // 0..3
  const int m_base = bm*128, n_base = bn*64;
  const int w = t >> 6, lane = t & 63;
  const int wr = (w >> 1)*64, wc = (w & 1)*32;
  const int fr = lane & 15, fk = lane >> 4;
  const int arow = t >> 1, acol = (t & 1)*16;
  const int brow = t >> 2, bcol = (t & 3)*8;

  v4f acc[4][2];
#pragma unroll
  for (int i = 0; i < 4; i++)
#pragma unroll
    for (int j = 0; j < 2; j++) acc[i][j] = (v4f){0.f,0.f,0.f,0.f};

  for (int k0 = 0; k0 < 512; k0 += 32) {
    __syncthreads();
    {
      int gm = m_base + arow;
      uint4 a0 = make_uint4(0u,0u,0u,0u), a1 = make_uint4(0u,0u,0u,0u);
      if (gm < N) {
        a0 = *(const uint4*)(att + (size_t)gm*512 + k0 + acol);
        a1 = *(const uint4*)(att + (size_t)gm*512 + k0 + acol + 8);
      }
      *(uint4*)&As[arow*40 + acol]     = a0;
      *(uint4*)&As[arow*40 + acol + 8] = a1;
      uint4 bv = loadpack8(wpost + (size_t)(n_base + brow)*512 + k0 + bcol);
      *(uint4*)&Bs[brow*40 + bcol] = bv;
    }
    __syncthreads();
    v8s b0 = *(const v8s*)&Bs[(wc      + fr)*40 + fk*8];
    v8s b1 = *(const v8s*)&Bs[(wc + 16 + fr)*40 + fk*8];
#pragma unroll
    for (int mi = 0; mi < 4; mi++) {
      v8s a = *(const v8s*)&As[(wr + mi*16 + fr)*40 + fk*8];
      acc[mi][0] = __builtin_amdgcn_mfma_f32_16x16x32_bf16(a,b0,acc[mi][0],0,0,0);
      acc[mi][1] = __builtin_amdgcn_mfma_f32_16x16x32_bf16(a,b1,acc[mi][1],0,0,0);
    }
  }
#pragma unroll
  for (int nj = 0; nj < 2; nj++) {
    int col = n_base + wc + nj*16 + fr;
    float bpv = bpost[col];
    float e   = __expf(ls[col]);
#pragma unroll
    for (int mi = 0; mi < 4; mi++) {
#pragma unroll
      for (int r = 0; r < 4; r++) {
        int row = m_base + wr + mi*16 + fk*4 + r;
        if (row < N) out0[(size_t)row*256 + col] = e*(acc[mi][nj][r] + bpv);
      }
    }
  }
}

// =====================================================================
extern "C" void kernel_launch(void* const* d_in, const int* in_sizes, int n_in,
                              void* d_out, int out_size, void* d_ws, size_t ws_size,
                              hipStream_t stream)
{
  const float* x     = (const float*)d_in[0];
  const float* xres  = (const float*)d_in[1];
  const int*   batch = (const int*)d_in[2];
  const float* wpre  = (const float*)d_in[4];
  const float* bpre  = (const float*)d_in[5];
  const float* wq    = (const float*)d_in[6];
  const float* wk    = (const float*)d_in[7];
  const float* wv    = (const float*)d_in[8];
  const float* wpost = (const float*)d_in[9];
  const float* bpost = (const float*)d_in[10];
  const float* ls    = (const float*)d_in[11];

  const int N = in_sizes[0] / 256;     // 20000 nodes
  const int B = in_sizes[1] / 8192;    // 1024 graphs
  const int nbm = (N + 127) / 128;     // 157 row tiles
  const int nchunk = (N + 255) / 256;  // 79 node chunks

  char* ws = (char*)d_ws;
  size_t off = 0;
  int*   flags  = (int*)(ws + off); off += 256;
  int*   bounds = (int*)(ws + off); off += ((size_t)B + 64) * 4;
  u16*   y      = (u16*)(ws + off);  off += (size_t)N * 512;   // bf16 y
  u16*   att    = (u16*)(ws + off);  off += (size_t)N * 1024;
  u16*   q      = (u16*)(ws + off);  off += (size_t)N * 1024;
  u16*   kten   = (u16*)(ws + off);  off += (size_t)N * 1024;
  u16*   vten   = (u16*)(ws + off);  off += (size_t)N * 1024;

  float* out0 = (float*)d_out;
  float* out1 = out0 + (size_t)N * 256;

  hipMemsetAsync(flags, 0, 4, stream);
  k_detect<<<nchunk,         256, 0, stream>>>(batch, N, flags);
  k_bounds<<<nchunk,         256, 0, stream>>>(batch, flags, N, B, bounds);
  k_pre   <<<nbm * 4,        256, 0, stream>>>(x, wpre, bpre, y, N, nbm);
  k_gnqkv <<<nchunk * 16,    256, 0, stream>>>(y, wq, wk, wv, q, kten, vten, N);
  k_segatt<<<B,              512, 0, stream>>>(kten, vten, q, xres, bounds,
                                               out1, att, N);
  k_post  <<<nbm * 4,        256, 0, stream>>>(att, wpost, bpost, ls, out0, N, nbm);
}

// Round 16
// 130.771 us; speedup vs baseline: 1.3337x; 1.0179x over previous
//
#include <hip/hip_runtime.h>
#include <stdint.h>

typedef unsigned int u32;
typedef unsigned short u16;
typedef __attribute__((ext_vector_type(8))) short v8s;   // 8 bf16 (4 VGPRs)
typedef __attribute__((ext_vector_type(4))) float v4f;   // 4 f32 acc

#define GN_EPS 1e-5f

// ---------- bf16 helpers (intermediates in ws are bf16) ----------
__device__ __forceinline__ float bflo(u32 u){ return __uint_as_float(u << 16); }
__device__ __forceinline__ float bfhi(u32 u){ return __uint_as_float(u & 0xffff0000u); }
__device__ __forceinline__ float bf1(u16 u){ return __uint_as_float((u32)u << 16); }
__device__ __forceinline__ u16 f2bf(float f){
  u32 x = __float_as_uint(f);
  u32 r = (x + 0x7fffu + ((x >> 16) & 1u)) >> 16;   // RNE
  return (u16)r;
}
__device__ __forceinline__ u32 pack2(float a, float b){
  return (u32)f2bf(a) | ((u32)f2bf(b) << 16);
}
__device__ __forceinline__ void unpack8(const uint4 u, float* f){
  f[0]=bflo(u.x); f[1]=bfhi(u.x); f[2]=bflo(u.y); f[3]=bfhi(u.y);
  f[4]=bflo(u.z); f[5]=bfhi(u.z); f[6]=bflo(u.w); f[7]=bfhi(u.w);
}
// load 8 f32, return packed bf16 (4 u32)
__device__ __forceinline__ uint4 loadpack8(const float* __restrict__ p){
  float4 a = *(const float4*)p, b = *(const float4*)(p + 4);
  return make_uint4(pack2(a.x,a.y),pack2(a.z,a.w),pack2(b.x,b.y),pack2(b.z,b.w));
}

// batch accessor: int32 or int64 (little-endian low word)
__device__ __forceinline__ int getb(const int* __restrict__ b, int is64, int i){
  return b[is64 ? 2*i : i];
}

// =====================================================================
// K0: detect batch int-width (parallel).
// =====================================================================
__global__ __launch_bounds__(256) void k_detect(
    const int* __restrict__ batch, int n, int* __restrict__ flags)
{
  int i = blockIdx.x*256 + threadIdx.x;
  int bad = 0;
  if (i < n - 1 && batch[i] > batch[i + 1]) bad = 1;
  if (__builtin_amdgcn_ballot_w64(bad) != 0 && (threadIdx.x & 63) == 0)
    atomicOr(&flags[0], 1);
}

// =====================================================================
// K0b: CSR bounds. bounds[g] = first node of graph g; bounds[B] = N.
// =====================================================================
__global__ __launch_bounds__(256) void k_bounds(
    const int* __restrict__ batch, const int* __restrict__ flags,
    int N, int B, int* __restrict__ bounds)
{
  int i = blockIdx.x*256 + threadIdx.x;
  if (i >= N) return;
  const int is64 = flags[0];
  int b = getb(batch, is64, i);
  int prev = (i == 0) ? -1 : getb(batch, is64, i - 1);
  for (int g = prev + 1; g <= b; g++) bounds[g] = i;
  if (i == N - 1)
    for (int g = b + 1; g <= B; g++) bounds[g] = N;
}

// =====================================================================
// K1 (MFMA): y = x @ w_pre^T + b_pre, bf16 out. Tile 128x64.
// =====================================================================
__global__ __launch_bounds__(256) void k_pre(
    const float* __restrict__ x, const float* __restrict__ wpre,
    const float* __restrict__ bpre, u16* __restrict__ y, int N, int nbm)
{
  __shared__ __align__(16) u16 As[128*40];
  __shared__ __align__(16) u16 Bs[64*40];
  const int t = threadIdx.x;
  const int bm = blockIdx.x % nbm;
  const int bn = blockIdx.x / nbm;          // 0..3
  const int m_base = bm*128, n_base = bn*64;
  const int w = t >> 6, lane = t & 63;
  const int wr = (w >> 1)*64, wc = (w & 1)*32;
  const int fr = lane & 15, fk = lane >> 4;
  const int arow = t >> 1, acol = (t & 1)*16;
  const int brow = t >> 2, bcol = (t & 3)*8;

  v4f acc[4][2];
#pragma unroll
  for (int i = 0; i < 4; i++)
#pragma unroll
    for (int j = 0; j < 2; j++) acc[i][j] = (v4f){0.f,0.f,0.f,0.f};

  for (int k0 = 0; k0 < 256; k0 += 32) {
    __syncthreads();
    {
      int gm = m_base + arow;
      uint4 a0 = make_uint4(0u,0u,0u,0u), a1 = make_uint4(0u,0u,0u,0u);
      if (gm < N) {
        a0 = loadpack8(x + (size_t)gm*256 + k0 + acol);
        a1 = loadpack8(x + (size_t)gm*256 + k0 + acol + 8);
      }
      *(uint4*)&As[arow*40 + acol]     = a0;
      *(uint4*)&As[arow*40 + acol + 8] = a1;
      uint4 bv = loadpack8(wpre + (size_t)(n_base + brow)*256 + k0 + bcol);
      *(uint4*)&Bs[brow*40 + bcol] = bv;
    }
    __syncthreads();
    v8s b0 = *(const v8s*)&Bs[(wc      + fr)*40 + fk*8];
    v8s b1 = *(const v8s*)&Bs[(wc + 16 + fr)*40 + fk*8];
#pragma unroll
    for (int mi = 0; mi < 4; mi++) {
      v8s a = *(const v8s*)&As[(wr + mi*16 + fr)*40 + fk*8];
      acc[mi][0] = __builtin_amdgcn_mfma_f32_16x16x32_bf16(a,b0,acc[mi][0],0,0,0);
      acc[mi][1] = __builtin_amdgcn_mfma_f32_16x16x32_bf16(a,b1,acc[mi][1],0,0,0);
    }
  }
#pragma unroll
  for (int nj = 0; nj < 2; nj++) {
    int col = n_base + wc + nj*16 + fr;
    float bpv = bpre[col];
#pragma unroll
    for (int mi = 0; mi < 4; mi++) {
#pragma unroll
      for (int r = 0; r < 4; r++) {
        int row = m_base + wr + mi*16 + fk*4 + r;
        if (row < N) y[(size_t)row*256 + col] = f2bf(acc[mi][nj][r] + bpv);
      }
    }
  }
}

// =====================================================================
// K2: block = (group g, 256-node chunk). Reads y bf16; GN in f32.
// =====================================================================
__global__ __launch_bounds__(256) void k_gnqkv(
    const u16* __restrict__ y, const float* __restrict__ wq,
    const float* __restrict__ wk, const float* __restrict__ wv,
    u16* __restrict__ qo, u16* __restrict__ ko, u16* __restrict__ vo, int N)
{
  __shared__ __align__(16) float wL[3*512];
  const int t = threadIdx.x;
  const int g = blockIdx.x & 15;
  const int c = blockIdx.x >> 4;
  {
    const float* srcs[3] = {wq, wk, wv};
#pragma unroll
    for (int tz = 0; tz < 3; tz++) {
      wL[tz*512 + t]       = srcs[tz][g*512 + t];
      wL[tz*512 + t + 256] = srcs[tz][g*512 + t + 256];
    }
  }
  __syncthreads();
  const int node = c*256 + t;
  if (node >= N) return;

  const u16* yp = y + (size_t)node*256 + g*16;
  uint4 Y0 = *(const uint4*)yp;
  uint4 Y1 = *(const uint4*)(yp + 8);
  float a[16]; unpack8(Y0, a); unpack8(Y1, a + 8);
  float mu = 0.f;
#pragma unroll
  for (int i = 0; i < 16; i++) mu += a[i];
  mu *= 0.0625f;
  float s2 = 0.f;
#pragma unroll
  for (int i = 0; i < 16; i++) { float d = a[i]-mu; s2 = fmaf(d,d,s2); }
  float inv = rsqrtf(s2*0.0625f + GN_EPS);
  float yn[16];
#pragma unroll
  for (int i = 0; i < 16; i++) yn[i] = (a[i]-mu)*inv;

  u16* outs[3] = {qo, ko, vo};
#pragma unroll
  for (int tz = 0; tz < 3; tz++) {
#pragma unroll
    for (int s = 0; s < 2; s++) {
      u32 p[8];
#pragma unroll
      for (int o = 0; o < 16; o++) {
        const float* row = &wL[tz*512 + (s*16 + o)*16];
        float4 W0 = *(const float4*)row;
        float4 W1 = *(const float4*)(row + 4);
        float4 W2 = *(const float4*)(row + 8);
        float4 W3 = *(const float4*)(row + 12);
        float w[16] = {W0.x,W0.y,W0.z,W0.w,W1.x,W1.y,W1.z,W1.w,
                       W2.x,W2.y,W2.z,W2.w,W3.x,W3.y,W3.z,W3.w};
        float d = 0.f;
#pragma unroll
        for (int i = 0; i < 16; i++) d = fmaf(yn[i], w[i], d);
        if (tz < 2) d = __expf(d*0.25f);
        if (o & 1) p[o>>1] |= (u32)f2bf(d) << 16;
        else       p[o>>1]  = (u32)f2bf(d);
      }
      u16* dst = outs[tz] + (size_t)node*512 + g*32 + s*16;
      *(uint4*)dst       = make_uint4(p[0],p[1],p[2],p[3]);
      *(uint4*)(dst + 8) = make_uint4(p[4],p[5],p[6],p[7]);
    }
  }
}

// =====================================================================
// K3 (512 threads, fused, reduction-free): thread (nh, d) owns output
// row KV[nh][d][0:16] and k_sum[nh][d]; accumulates over ALL graph
// nodes (no cross-thread reduction, no barriers in phase 1).
// LDS = kvs bf16 (17.5K) + kss (2.2K) ~ 20KB -> 4 blocks/CU.
// Phase 2: out1 = KV + xres (64B/thread contiguous); kv -> LDS bf16.
// Phase 3: att from LDS-resident kv (round-8 code).
// =====================================================================
__global__ __launch_bounds__(512) void k_segatt(
    const u16* __restrict__ xk, const u16* __restrict__ xv,
    const u16* __restrict__ xq, const float* __restrict__ xres,
    const int* __restrict__ bounds,
    float* __restrict__ out1, u16* __restrict__ att, int N)
{
  __shared__ __align__(16) u16 kvs[32*280];     // 17.5 KB
  __shared__ float kss[32*17];                  // 2.2 KB
  const int b = blockIdx.x, t = threadIdx.x;
  const int lo = bounds[b], hi = bounds[b+1];
  const int nh = t >> 4, d = t & 15;

  float kv[16];
#pragma unroll
  for (int v = 0; v < 16; v++) kv[v] = 0.f;
  float ks = 0.f;

  // ---- phase 1: direct-from-global, no barriers, unroll x2 ----
  const size_t koff = (size_t)nh*16 + d;
  const size_t voff = (size_t)nh*16;
  int node = lo;
  for (; node + 1 < hi; node += 2) {
    u16  ka  = xk[(size_t)node*512 + koff];
    uint4 Va0 = *(const uint4*)(xv + (size_t)node*512 + voff);
    uint4 Va1 = *(const uint4*)(xv + (size_t)node*512 + voff + 8);
    u16  kb  = xk[(size_t)(node+1)*512 + koff];
    uint4 Vb0 = *(const uint4*)(xv + (size_t)(node+1)*512 + voff);
    uint4 Vb1 = *(const uint4*)(xv + (size_t)(node+1)*512 + voff + 8);
    float k0 = bf1(ka), k1 = bf1(kb);
    float va[16], vb[16];
    unpack8(Va0, va); unpack8(Va1, va + 8);
    unpack8(Vb0, vb); unpack8(Vb1, vb + 8);
    ks += k0 + k1;
#pragma unroll
    for (int v = 0; v < 16; v++) {
      kv[v] = fmaf(k0, va[v], kv[v]);
      kv[v] = fmaf(k1, vb[v], kv[v]);
    }
  }
  if (node < hi) {
    u16  ka  = xk[(size_t)node*512 + koff];
    uint4 V0 = *(const uint4*)(xv + (size_t)node*512 + voff);
    uint4 V1 = *(const uint4*)(xv + (size_t)node*512 + voff + 8);
    float k0 = bf1(ka);
    float vf[16]; unpack8(V0, vf); unpack8(V1, vf + 8);
    ks += k0;
#pragma unroll
    for (int v = 0; v < 16; v++) kv[v] = fmaf(k0, vf[v], kv[v]);
  }

  kss[nh*17 + d] = ks;

  // ---- phase 2: out1 = kv + xres; kv -> LDS (bf16) ----
  {
    size_t idx = ((size_t)(b*32 + nh)*16 + d)*16;
    const float* xp = xres + idx;
    float4 X0 = *(const float4*)xp;
    float4 X1 = *(const float4*)(xp + 4);
    float4 X2 = *(const float4*)(xp + 8);
    float4 X3 = *(const float4*)(xp + 12);
    float xf[16] = {X0.x,X0.y,X0.z,X0.w,X1.x,X1.y,X1.z,X1.w,
                    X2.x,X2.y,X2.z,X2.w,X3.x,X3.y,X3.z,X3.w};
    float o[16];
#pragma unroll
    for (int j = 0; j < 16; j++) o[j] = kv[j] + xf[j];
    float* op = out1 + idx;
    *(float4*)op        = make_float4(o[0],o[1],o[2],o[3]);
    *(float4*)(op + 4)  = make_float4(o[4],o[5],o[6],o[7]);
    *(float4*)(op + 8)  = make_float4(o[8],o[9],o[10],o[11]);
    *(float4*)(op + 12) = make_float4(o[12],o[13],o[14],o[15]);
    u16* lp = &kvs[nh*280 + d*16];
    *(uint4*)lp       = make_uint4(pack2(o[0],o[1]),  pack2(o[2],o[3]),
                                   pack2(o[4],o[5]),  pack2(o[6],o[7]));
    *(uint4*)(lp + 8) = make_uint4(pack2(o[8],o[9]),  pack2(o[10],o[11]),
                                   pack2(o[12],o[13]),pack2(o[14],o[15]));
  }
  __syncthreads();

  // ---- phase 3: att, 16 node-slots per iter ----
  const int nh2 = t & 31, ns = t >> 5;   // ns 0..15
  for (int n0 = lo; n0 < hi; n0 += 16) {
    int nodei = n0 + ns;
    if (nodei >= hi) continue;
    const u16* qp = xq + (size_t)nodei*512 + nh2*16;
    uint4 Q0 = *(const uint4*)qp;
    uint4 Q1 = *(const uint4*)(qp + 8);
    float q[16]; unpack8(Q0, q); unpack8(Q1, q + 8);
    const float* ksp = &kss[nh2*17];
    float denom = 0.f;
#pragma unroll
    for (int i = 0; i < 16; i++) denom = fmaf(q[i], ksp[i], denom);
    float inv = 1.0f / fmaxf(denom, 1e-20f);
    float a[16];
#pragma unroll
    for (int v = 0; v < 16; v++) a[v] = 0.f;
    const u16* kvp = &kvs[nh2*280];
#pragma unroll
    for (int h = 0; h < 16; h++) {
      float qh = q[h] * inv;
      uint4 W0 = *(const uint4*)(kvp + h*16);
      uint4 W1 = *(const uint4*)(kvp + h*16 + 8);
      float w[16]; unpack8(W0, w); unpack8(W1, w + 8);
#pragma unroll
      for (int v = 0; v < 16; v++) a[v] = fmaf(qh, w[v], a[v]);
    }
    u32 p[8];
#pragma unroll
    for (int j = 0; j < 8; j++) p[j] = pack2(a[2*j], a[2*j+1]);
    u16* dst = att + (size_t)nodei*512 + nh2*16;
    *(uint4*)dst       = make_uint4(p[0],p[1],p[2],p[3]);
    *(uint4*)(dst + 8) = make_uint4(p[4],p[5],p[6],p[7]);
  }
}

// =====================================================================
// K5 (MFMA): out0 = exp(log_scale) * (att @ w_post^T + b_post), K=512.
// Tile 128x64.
// =====================================================================
__global__ __launch_bounds__(256) void k_post(
    const u16* __restrict__ att, const float* __restrict__ wpost,
    const float* __restrict__ bpost, const float* __restrict__ ls,
    float* __restrict__ out0, int N, int nbm)
{
  __shared__ __align__(16) u16 As[128*40];
  __shared__ __align__(16) u16 Bs[64*40];
  const int t = threadIdx.x;
  const int bm = blockIdx.x % nbm;
  const int bn = blockIdx.x / nbm;          // 0..3
  const int m_base = bm*128, n_base = bn*64;
  const int w = t >> 6, lane = t & 63;
  const int wr = (w >> 1)*64, wc = (w & 1)*32;
  const int fr = lane & 15, fk = lane >> 4;
  const int arow = t >> 1, acol = (t & 1)*16;
  const int brow = t >> 2, bcol = (t & 3)*8;

  v4f acc[4][2];
#pragma unroll
  for (int i = 0; i < 4; i++)
#pragma unroll
    for (int j = 0; j < 2; j++) acc[i][j] = (v4f){0.f,0.f,0.f,0.f};

  for (int k0 = 0; k0 < 512; k0 += 32) {
    __syncthreads();
    {
      int gm = m_base + arow;
      uint4 a0 = make_uint4(0u,0u,0u,0u), a1 = make_uint4(0u,0u,0u,0u);
      if (gm < N) {
        a0 = *(const uint4*)(att + (size_t)gm*512 + k0 + acol);
        a1 = *(const uint4*)(att + (size_t)gm*512 + k0 + acol + 8);
      }
      *(uint4*)&As[arow*40 + acol]     = a0;
      *(uint4*)&As[arow*40 + acol + 8] = a1;
      uint4 bv = loadpack8(wpost + (size_t)(n_base + brow)*512 + k0 + bcol);
      *(uint4*)&Bs[brow*40 + bcol] = bv;
    }
    __syncthreads();
    v8s b0 = *(const v8s*)&Bs[(wc      + fr)*40 + fk*8];
    v8s b1 = *(const v8s*)&Bs[(wc + 16 + fr)*40 + fk*8];
#pragma unroll
    for (int mi = 0; mi < 4; mi++) {
      v8s a = *(const v8s*)&As[(wr + mi*16 + fr)*40 + fk*8];
      acc[mi][0] = __builtin_amdgcn_mfma_f32_16x16x32_bf16(a,b0,acc[mi][0],0,0,0);
      acc[mi][1] = __builtin_amdgcn_mfma_f32_16x16x32_bf16(a,b1,acc[mi][1],0,0,0);
    }
  }
#pragma unroll
  for (int nj = 0; nj < 2; nj++) {
    int col = n_base + wc + nj*16 + fr;
    float bpv = bpost[col];
    float e   = __expf(ls[col]);
#pragma unroll
    for (int mi = 0; mi < 4; mi++) {
#pragma unroll
      for (int r = 0; r < 4; r++) {
        int row = m_base + wr + mi*16 + fk*4 + r;
        if (row < N) out0[(size_t)row*256 + col] = e*(acc[mi][nj][r] + bpv);
      }
    }
  }
}

// =====================================================================
extern "C" void kernel_launch(void* const* d_in, const int* in_sizes, int n_in,
                              void* d_out, int out_size, void* d_ws, size_t ws_size,
                              hipStream_t stream)
{
  const float* x     = (const float*)d_in[0];
  const float* xres  = (const float*)d_in[1];
  const int*   batch = (const int*)d_in[2];
  const float* wpre  = (const float*)d_in[4];
  const float* bpre  = (const float*)d_in[5];
  const float* wq    = (const float*)d_in[6];
  const float* wk    = (const float*)d_in[7];
  const float* wv    = (const float*)d_in[8];
  const float* wpost = (const float*)d_in[9];
  const float* bpost = (const float*)d_in[10];
  const float* ls    = (const float*)d_in[11];

  const int N = in_sizes[0] / 256;     // 20000 nodes
  const int B = in_sizes[1] / 8192;    // 1024 graphs
  const int nbm = (N + 127) / 128;     // 157 row tiles
  const int nchunk = (N + 255) / 256;  // 79 node chunks

  char* ws = (char*)d_ws;
  size_t off = 0;
  int*   flags  = (int*)(ws + off); off += 256;
  int*   bounds = (int*)(ws + off); off += ((size_t)B + 64) * 4;
  u16*   y      = (u16*)(ws + off);  off += (size_t)N * 512;   // bf16 y
  u16*   att    = (u16*)(ws + off);  off += (size_t)N * 1024;
  u16*   q      = (u16*)(ws + off);  off += (size_t)N * 1024;
  u16*   kten   = (u16*)(ws + off);  off += (size_t)N * 1024;
  u16*   vten   = (u16*)(ws + off);  off += (size_t)N * 1024;

  float* out0 = (float*)d_out;
  float* out1 = out0 + (size_t)N * 256;

  hipMemsetAsync(flags, 0, 4, stream);
  k_detect<<<nchunk,         256, 0, stream>>>(batch, N, flags);
  k_bounds<<<nchunk,         256, 0, stream>>>(batch, flags, N, B, bounds);
  k_pre   <<<nbm * 4,        256, 0, stream>>>(x, wpre, bpre, y, N, nbm);
  k_gnqkv <<<nchunk * 16,    256, 0, stream>>>(y, wq, wk, wv, q, kten, vten, N);
  k_segatt<<<B,              512, 0, stream>>>(kten, vten, q, xres, bounds,
                                               out1, att, N);
  k_post  <<<nbm * 4,        256, 0, stream>>>(att, wpost, bpost, ls, out0, N, nbm);
}

// Round 17
// 128.208 us; speedup vs baseline: 1.3603x; 1.0200x over previous
//
#include <hip/hip_runtime.h>
#include <stdint.h>

typedef unsigned int u32;
typedef unsigned short u16;
typedef __attribute__((ext_vector_type(8))) short v8s;   // 8 bf16 (4 VGPRs)
typedef __attribute__((ext_vector_type(4))) float v4f;   // 4 f32 acc

#define GN_EPS 1e-5f

// ---------- bf16 helpers (intermediates in ws are bf16) ----------
__device__ __forceinline__ float bflo(u32 u){ return __uint_as_float(u << 16); }
__device__ __forceinline__ float bfhi(u32 u){ return __uint_as_float(u & 0xffff0000u); }
__device__ __forceinline__ float bf1(u16 u){ return __uint_as_float((u32)u << 16); }
__device__ __forceinline__ u16 f2bf(float f){
  u32 x = __float_as_uint(f);
  u32 r = (x + 0x7fffu + ((x >> 16) & 1u)) >> 16;   // RNE
  return (u16)r;
}
__device__ __forceinline__ u32 pack2(float a, float b){
  return (u32)f2bf(a) | ((u32)f2bf(b) << 16);
}
__device__ __forceinline__ void unpack8(const uint4 u, float* f){
  f[0]=bflo(u.x); f[1]=bfhi(u.x); f[2]=bflo(u.y); f[3]=bfhi(u.y);
  f[4]=bflo(u.z); f[5]=bfhi(u.z); f[6]=bflo(u.w); f[7]=bfhi(u.w);
}
// load 8 f32, return packed bf16 (4 u32)
__device__ __forceinline__ uint4 loadpack8(const float* __restrict__ p){
  float4 a = *(const float4*)p, b = *(const float4*)(p + 4);
  return make_uint4(pack2(a.x,a.y),pack2(a.z,a.w),pack2(b.x,b.y),pack2(b.z,b.w));
}
__device__ __forceinline__ float dot16(const float* __restrict__ yn,
                                       const float* __restrict__ row){
  float4 W0 = *(const float4*)row;
  float4 W1 = *(const float4*)(row + 4);
  float4 W2 = *(const float4*)(row + 8);
  float4 W3 = *(const float4*)(row + 12);
  float d = 0.f;
  d = fmaf(yn[0],W0.x,d); d = fmaf(yn[1],W0.y,d);
  d = fmaf(yn[2],W0.z,d); d = fmaf(yn[3],W0.w,d);
  d = fmaf(yn[4],W1.x,d); d = fmaf(yn[5],W1.y,d);
  d = fmaf(yn[6],W1.z,d); d = fmaf(yn[7],W1.w,d);
  d = fmaf(yn[8],W2.x,d); d = fmaf(yn[9],W2.y,d);
  d = fmaf(yn[10],W2.z,d); d = fmaf(yn[11],W2.w,d);
  d = fmaf(yn[12],W3.x,d); d = fmaf(yn[13],W3.y,d);
  d = fmaf(yn[14],W3.z,d); d = fmaf(yn[15],W3.w,d);
  return d;
}
__device__ __forceinline__ float rsum16(float v){
  v += __shfl_xor(v, 1);
  v += __shfl_xor(v, 2);
  v += __shfl_xor(v, 4);
  v += __shfl_xor(v, 8);
  return v;
}

// batch accessor: int32 or int64 (little-endian low word)
__device__ __forceinline__ int getb(const int* __restrict__ b, int is64, int i){
  return b[is64 ? 2*i : i];
}

// =====================================================================
// K0: detect batch int-width (parallel).
// =====================================================================
__global__ __launch_bounds__(256) void k_detect(
    const int* __restrict__ batch, int n, int* __restrict__ flags)
{
  int i = blockIdx.x*256 + threadIdx.x;
  int bad = 0;
  if (i < n - 1 && batch[i] > batch[i + 1]) bad = 1;
  if (__builtin_amdgcn_ballot_w64(bad) != 0 && (threadIdx.x & 63) == 0)
    atomicOr(&flags[0], 1);
}

// =====================================================================
// K0b: CSR bounds. bounds[g] = first node of graph g; bounds[B] = N.
// =====================================================================
__global__ __launch_bounds__(256) void k_bounds(
    const int* __restrict__ batch, const int* __restrict__ flags,
    int N, int B, int* __restrict__ bounds)
{
  int i = blockIdx.x*256 + threadIdx.x;
  if (i >= N) return;
  const int is64 = flags[0];
  int b = getb(batch, is64, i);
  int prev = (i == 0) ? -1 : getb(batch, is64, i - 1);
  for (int g = prev + 1; g <= b; g++) bounds[g] = i;
  if (i == N - 1)
    for (int g = b + 1; g <= B; g++) bounds[g] = N;
}

// =====================================================================
// K1 (fused MFMA GEMM + GroupNorm + grouped QKV convs).
// Tile 128 nodes x 64 cols (= 4 complete groups). After the K-loop:
//  - y = acc + bias stays in regs; GN mean/var via 4x shfl_xor over the
//    16 fr-lanes that hold one group row; yn (bf16) -> ynL.
//  - barrier; stage wq/wk/wv for the tile's 4 groups into wL (aliases
//    the GEMM As/Bs region; stride 520 f32 -> conflict-free broadcast).
//  - barrier; conv phase: thread = (node, group) x2; q,k get exp(.*0.25).
// =====================================================================
__global__ __launch_bounds__(256) void k_prefused(
    const float* __restrict__ x, const float* __restrict__ wpre,
    const float* __restrict__ bpre,
    const float* __restrict__ wq, const float* __restrict__ wk,
    const float* __restrict__ wv,
    u16* __restrict__ qo, u16* __restrict__ ko, u16* __restrict__ vo,
    int N, int nbm)
{
  __shared__ __align__(16) char SMEM[25600];    // As/Bs (15.3K) then wL (25K)
  __shared__ __align__(16) u16 ynL[128*72];     // 18 KB, 144B rows (16B-aligned)
  u16* As = (u16*)SMEM;                         // 128*40
  u16* Bs = (u16*)(SMEM + 128*40*2);            // 64*40
  float* wL = (float*)SMEM;                     // 3*2080 f32 after barrier

  const int t = threadIdx.x;
  const int bm = blockIdx.x % nbm;
  const int bn = blockIdx.x / nbm;              // 0..3
  const int m_base = bm*128, n_base = bn*64;
  const int w = t >> 6, lane = t & 63;
  const int wr = (w >> 1)*64, wc = (w & 1)*32;
  const int fr = lane & 15, fk = lane >> 4;
  const int arow = t >> 1, acol = (t & 1)*16;
  const int brow = t >> 2, bcol = (t & 3)*8;

  v4f acc[4][2];
#pragma unroll
  for (int i = 0; i < 4; i++)
#pragma unroll
    for (int j = 0; j < 2; j++) acc[i][j] = (v4f){0.f,0.f,0.f,0.f};

  for (int k0 = 0; k0 < 256; k0 += 32) {
    __syncthreads();
    {
      int gm = m_base + arow;
      uint4 a0 = make_uint4(0u,0u,0u,0u), a1 = make_uint4(0u,0u,0u,0u);
      if (gm < N) {
        a0 = loadpack8(x + (size_t)gm*256 + k0 + acol);
        a1 = loadpack8(x + (size_t)gm*256 + k0 + acol + 8);
      }
      *(uint4*)&As[arow*40 + acol]     = a0;
      *(uint4*)&As[arow*40 + acol + 8] = a1;
      uint4 bv = loadpack8(wpre + (size_t)(n_base + brow)*256 + k0 + bcol);
      *(uint4*)&Bs[brow*40 + bcol] = bv;
    }
    __syncthreads();
    v8s b0 = *(const v8s*)&Bs[(wc      + fr)*40 + fk*8];
    v8s b1 = *(const v8s*)&Bs[(wc + 16 + fr)*40 + fk*8];
#pragma unroll
    for (int mi = 0; mi < 4; mi++) {
      v8s a = *(const v8s*)&As[(wr + mi*16 + fr)*40 + fk*8];
      acc[mi][0] = __builtin_amdgcn_mfma_f32_16x16x32_bf16(a,b0,acc[mi][0],0,0,0);
      acc[mi][1] = __builtin_amdgcn_mfma_f32_16x16x32_bf16(a,b1,acc[mi][1],0,0,0);
    }
  }

  // ---- epilogue: GroupNorm in-register, yn -> ynL ----
#pragma unroll
  for (int nj = 0; nj < 2; nj++) {
    int col = n_base + wc + nj*16 + fr;
    float bpv = bpre[col];
    int gloc = (w & 1)*2 + nj;                  // group within tile 0..3
#pragma unroll
    for (int mi = 0; mi < 4; mi++) {
#pragma unroll
      for (int r = 0; r < 4; r++) {
        float yv = acc[mi][nj][r] + bpv;
        float s1 = rsum16(yv);
        float s2 = rsum16(yv*yv);
        float mu = s1 * 0.0625f;
        float var = fmaxf(s2*0.0625f - mu*mu, 0.f);
        float ynv = (yv - mu) * rsqrtf(var + GN_EPS);
        int row = wr + mi*16 + fk*4 + r;        // 0..127
        ynL[row*72 + gloc*16 + fr] = f2bf(ynv);
      }
    }
  }
  __syncthreads();   // MFMA LDS reads done; ynL published

  // ---- stage qkv weights for this tile's 4 groups (over As/Bs) ----
  {
    const float* srcs[3] = {wq, wk, wv};
#pragma unroll
    for (int tz = 0; tz < 3; tz++) {
      for (int i = t; i < 2048; i += 256) {
        int gi = i >> 9, rem = i & 511;
        wL[tz*2080 + gi*520 + rem] = srcs[tz][((size_t)(bn*4 + gi))*512 + rem];
      }
    }
  }
  __syncthreads();

  // ---- conv phase: thread = (node, group) pair, x2 ----
  u16* outs[3] = {qo, ko, vo};
#pragma unroll
  for (int p = 0; p < 2; p++) {
    int idx = p*256 + t;                        // 0..511
    int nloc = idx >> 2, gl = idx & 3;
    int node = m_base + nloc;
    if (node >= N) continue;
    uint4 Y0 = *(const uint4*)&ynL[nloc*72 + gl*16];
    uint4 Y1 = *(const uint4*)&ynL[nloc*72 + gl*16 + 8];
    float yn[16]; unpack8(Y0, yn); unpack8(Y1, yn + 8);
    int g = bn*4 + gl;
#pragma unroll
    for (int tz = 0; tz < 3; tz++) {
#pragma unroll
      for (int s = 0; s < 2; s++) {
        u32 pk[8];
#pragma unroll
        for (int o = 0; o < 16; o++) {
          float d = dot16(yn, &wL[tz*2080 + gl*520 + (s*16 + o)*16]);
          if (tz < 2) d = __expf(d*0.25f);
          if (o & 1) pk[o>>1] |= (u32)f2bf(d) << 16;
          else       pk[o>>1]  = (u32)f2bf(d);
        }
        u16* dst = outs[tz] + (size_t)node*512 + g*32 + s*16;
        *(uint4*)dst       = make_uint4(pk[0],pk[1],pk[2],pk[3]);
        *(uint4*)(dst + 8) = make_uint4(pk[4],pk[5],pk[6],pk[7]);
      }
    }
  }
}

// =====================================================================
// K3 (512 threads, fused, reduction-free): thread (nh, d) owns output
// row KV[nh][d][0:16] and k_sum[nh][d]; accumulates over ALL graph
// nodes. LDS ~20KB. Phase 2: out1 = KV + xres; kv -> LDS bf16.
// Phase 3: att from LDS-resident kv.
// =====================================================================
__global__ __launch_bounds__(512) void k_segatt(
    const u16* __restrict__ xk, const u16* __restrict__ xv,
    const u16* __restrict__ xq, const float* __restrict__ xres,
    const int* __restrict__ bounds,
    float* __restrict__ out1, u16* __restrict__ att, int N)
{
  __shared__ __align__(16) u16 kvs[32*280];     // 17.5 KB
  __shared__ float kss[32*17];                  // 2.2 KB
  const int b = blockIdx.x, t = threadIdx.x;
  const int lo = bounds[b], hi = bounds[b+1];
  const int nh = t >> 4, d = t & 15;

  float kv[16];
#pragma unroll
  for (int v = 0; v < 16; v++) kv[v] = 0.f;
  float ks = 0.f;

  const size_t koff = (size_t)nh*16 + d;
  const size_t voff = (size_t)nh*16;
  int node = lo;
  for (; node + 1 < hi; node += 2) {
    u16  ka  = xk[(size_t)node*512 + koff];
    uint4 Va0 = *(const uint4*)(xv + (size_t)node*512 + voff);
    uint4 Va1 = *(const uint4*)(xv + (size_t)node*512 + voff + 8);
    u16  kb  = xk[(size_t)(node+1)*512 + koff];
    uint4 Vb0 = *(const uint4*)(xv + (size_t)(node+1)*512 + voff);
    uint4 Vb1 = *(const uint4*)(xv + (size_t)(node+1)*512 + voff + 8);
    float k0 = bf1(ka), k1 = bf1(kb);
    float va[16], vb[16];
    unpack8(Va0, va); unpack8(Va1, va + 8);
    unpack8(Vb0, vb); unpack8(Vb1, vb + 8);
    ks += k0 + k1;
#pragma unroll
    for (int v = 0; v < 16; v++) {
      kv[v] = fmaf(k0, va[v], kv[v]);
      kv[v] = fmaf(k1, vb[v], kv[v]);
    }
  }
  if (node < hi) {
    u16  ka  = xk[(size_t)node*512 + koff];
    uint4 V0 = *(const uint4*)(xv + (size_t)node*512 + voff);
    uint4 V1 = *(const uint4*)(xv + (size_t)node*512 + voff + 8);
    float k0 = bf1(ka);
    float vf[16]; unpack8(V0, vf); unpack8(V1, vf + 8);
    ks += k0;
#pragma unroll
    for (int v = 0; v < 16; v++) kv[v] = fmaf(k0, vf[v], kv[v]);
  }

  kss[nh*17 + d] = ks;

  {
    size_t idx = ((size_t)(b*32 + nh)*16 + d)*16;
    const float* xp = xres + idx;
    float4 X0 = *(const float4*)xp;
    float4 X1 = *(const float4*)(xp + 4);
    float4 X2 = *(const float4*)(xp + 8);
    float4 X3 = *(const float4*)(xp + 12);
    float xf[16] = {X0.x,X0.y,X0.z,X0.w,X1.x,X1.y,X1.z,X1.w,
                    X2.x,X2.y,X2.z,X2.w,X3.x,X3.y,X3.z,X3.w};
    float o[16];
#pragma unroll
    for (int j = 0; j < 16; j++) o[j] = kv[j] + xf[j];
    float* op = out1 + idx;
    *(float4*)op        = make_float4(o[0],o[1],o[2],o[3]);
    *(float4*)(op + 4)  = make_float4(o[4],o[5],o[6],o[7]);
    *(float4*)(op + 8)  = make_float4(o[8],o[9],o[10],o[11]);
    *(float4*)(op + 12) = make_float4(o[12],o[13],o[14],o[15]);
    u16* lp = &kvs[nh*280 + d*16];
    *(uint4*)lp       = make_uint4(pack2(o[0],o[1]),  pack2(o[2],o[3]),
                                   pack2(o[4],o[5]),  pack2(o[6],o[7]));
    *(uint4*)(lp + 8) = make_uint4(pack2(o[8],o[9]),  pack2(o[10],o[11]),
                                   pack2(o[12],o[13]),pack2(o[14],o[15]));
  }
  __syncthreads();

  const int nh2 = t & 31, ns = t >> 5;   // ns 0..15
  for (int n0 = lo; n0 < hi; n0 += 16) {
    int nodei = n0 + ns;
    if (nodei >= hi) continue;
    const u16* qp = xq + (size_t)nodei*512 + nh2*16;
    uint4 Q0 = *(const uint4*)qp;
    uint4 Q1 = *(const uint4*)(qp + 8);
    float q[16]; unpack8(Q0, q); unpack8(Q1, q + 8);
    const float* ksp = &kss[nh2*17];
    float denom = 0.f;
#pragma unroll
    for (int i = 0; i < 16; i++) denom = fmaf(q[i], ksp[i], denom);
    float inv = 1.0f / fmaxf(denom, 1e-20f);
    float a[16];
#pragma unroll
    for (int v = 0; v < 16; v++) a[v] = 0.f;
    const u16* kvp = &kvs[nh2*280];
#pragma unroll
    for (int h = 0; h < 16; h++) {
      float qh = q[h] * inv;
      uint4 W0 = *(const uint4*)(kvp + h*16);
      uint4 W1 = *(const uint4*)(kvp + h*16 + 8);
      float wv2[16]; unpack8(W0, wv2); unpack8(W1, wv2 + 8);
#pragma unroll
      for (int v = 0; v < 16; v++) a[v] = fmaf(qh, wv2[v], a[v]);
    }
    u32 p[8];
#pragma unroll
    for (int j = 0; j < 8; j++) p[j] = pack2(a[2*j], a[2*j+1]);
    u16* dst = att + (size_t)nodei*512 + nh2*16;
    *(uint4*)dst       = make_uint4(p[0],p[1],p[2],p[3]);
    *(uint4*)(dst + 8) = make_uint4(p[4],p[5],p[6],p[7]);
  }
}

// =====================================================================
// K5 (MFMA): out0 = exp(log_scale) * (att @ w_post^T + b_post), K=512.
// Tile 128x64.
// =====================================================================
__global__ __launch_bounds__(256) void k_post(
    const u16* __restrict__ att, const float* __restrict__ wpost,
    const float* __restrict__ bpost, const float* __restrict__ ls,
    float* __restrict__ out0, int N, int nbm)
{
  __shared__ __align__(16) u16 As[128*40];
  __shared__ __align__(16) u16 Bs[64*40];
  const int t = threadIdx.x;
  const int bm = blockIdx.x % nbm;
  const int bn = blockIdx.x / nbm;          // 0..3
  const int m_base = bm*128, n_base = bn*64;
  const int w = t >> 6, lane = t & 63;
  const int wr = (w >> 1)*64, wc = (w & 1)*32;
  const int fr = lane & 15, fk = lane >> 4;
  const int arow = t >> 1, acol = (t & 1)*16;
  const int brow = t >> 2, bcol = (t & 3)*8;

  v4f acc[4][2];
#pragma unroll
  for (int i = 0; i < 4; i++)
#pragma unroll
    for (int j = 0; j < 2; j++) acc[i][j] = (v4f){0.f,0.f,0.f,0.f};

  for (int k0 = 0; k0 < 512; k0 += 32) {
    __syncthreads();
    {
      int gm = m_base + arow;
      uint4 a0 = make_uint4(0u,0u,0u,0u), a1 = make_uint4(0u,0u,0u,0u);
      if (gm < N) {
        a0 = *(const uint4*)(att + (size_t)gm*512 + k0 + acol);
        a1 = *(const uint4*)(att + (size_t)gm*512 + k0 + acol + 8);
      }
      *(uint4*)&As[arow*40 + acol]     = a0;
      *(uint4*)&As[arow*40 + acol + 8] = a1;
      uint4 bv = loadpack8(wpost + (size_t)(n_base + brow)*512 + k0 + bcol);
      *(uint4*)&Bs[brow*40 + bcol] = bv;
    }
    __syncthreads();
    v8s b0 = *(const v8s*)&Bs[(wc      + fr)*40 + fk*8];
    v8s b1 = *(const v8s*)&Bs[(wc + 16 + fr)*40 + fk*8];
#pragma unroll
    for (int mi = 0; mi < 4; mi++) {
      v8s a = *(const v8s*)&As[(wr + mi*16 + fr)*40 + fk*8];
      acc[mi][0] = __builtin_amdgcn_mfma_f32_16x16x32_bf16(a,b0,acc[mi][0],0,0,0);
      acc[mi][1] = __builtin_amdgcn_mfma_f32_16x16x32_bf16(a,b1,acc[mi][1],0,0,0);
    }
  }
#pragma unroll
  for (int nj = 0; nj < 2; nj++) {
    int col = n_base + wc + nj*16 + fr;
    float bpv = bpost[col];
    float e   = __expf(ls[col]);
#pragma unroll
    for (int mi = 0; mi < 4; mi++) {
#pragma unroll
      for (int r = 0; r < 4; r++) {
        int row = m_base + wr + mi*16 + fk*4 + r;
        if (row < N) out0[(size_t)row*256 + col] = e*(acc[mi][nj][r] + bpv);
      }
    }
  }
}

// =====================================================================
extern "C" void kernel_launch(void* const* d_in, const int* in_sizes, int n_in,
                              void* d_out, int out_size, void* d_ws, size_t ws_size,
                              hipStream_t stream)
{
  const float* x     = (const float*)d_in[0];
  const float* xres  = (const float*)d_in[1];
  const int*   batch = (const int*)d_in[2];
  const float* wpre  = (const float*)d_in[4];
  const float* bpre  = (const float*)d_in[5];
  const float* wq    = (const float*)d_in[6];
  const float* wk    = (const float*)d_in[7];
  const float* wv    = (const float*)d_in[8];
  const float* wpost = (const float*)d_in[9];
  const float* bpost = (const float*)d_in[10];
  const float* ls    = (const float*)d_in[11];

  const int N = in_sizes[0] / 256;     // 20000 nodes
  const int B = in_sizes[1] / 8192;    // 1024 graphs
  const int nbm = (N + 127) / 128;     // 157 row tiles
  const int nchunk = (N + 255) / 256;  // 79 node chunks

  char* ws = (char*)d_ws;
  size_t off = 0;
  int*   flags  = (int*)(ws + off); off += 256;
  int*   bounds = (int*)(ws + off); off += ((size_t)B + 64) * 4;
  u16*   att    = (u16*)(ws + off);  off += (size_t)N * 1024;
  u16*   q      = (u16*)(ws + off);  off += (size_t)N * 1024;
  u16*   kten   = (u16*)(ws + off);  off += (size_t)N * 1024;
  u16*   vten   = (u16*)(ws + off);  off += (size_t)N * 1024;

  float* out0 = (float*)d_out;
  float* out1 = out0 + (size_t)N * 256;

  hipMemsetAsync(flags, 0, 4, stream);
  k_detect  <<<nchunk,        256, 0, stream>>>(batch, N, flags);
  k_bounds  <<<nchunk,        256, 0, stream>>>(batch, flags, N, B, bounds);
  k_prefused<<<nbm * 4,       256, 0, stream>>>(x, wpre, bpre, wq, wk, wv,
                                                q, kten, vten, N, nbm);
  k_segatt  <<<B,             512, 0, stream>>>(kten, vten, q, xres, bounds,
                                                out1, att, N);
  k_post    <<<nbm * 4,       256, 0, stream>>>(att, wpost, bpost, ls, out0, N, nbm);
}

// Round 18
// 128.030 us; speedup vs baseline: 1.3622x; 1.0014x over previous
//
#include <hip/hip_runtime.h>
#include <stdint.h>

typedef unsigned int u32;
typedef unsigned short u16;
typedef __attribute__((ext_vector_type(8))) short v8s;   // 8 bf16 (4 VGPRs)
typedef __attribute__((ext_vector_type(4))) float v4f;   // 4 f32 acc

#define GN_EPS 1e-5f

// ---------- bf16 helpers (intermediates in ws are bf16) ----------
__device__ __forceinline__ float bflo(u32 u){ return __uint_as_float(u << 16); }
__device__ __forceinline__ float bfhi(u32 u){ return __uint_as_float(u & 0xffff0000u); }
__device__ __forceinline__ float bf1(u16 u){ return __uint_as_float((u32)u << 16); }
__device__ __forceinline__ u16 f2bf(float f){
  u32 x = __float_as_uint(f);
  u32 r = (x + 0x7fffu + ((x >> 16) & 1u)) >> 16;   // RNE
  return (u16)r;
}
__device__ __forceinline__ u32 pack2(float a, float b){
  return (u32)f2bf(a) | ((u32)f2bf(b) << 16);
}
__device__ __forceinline__ void unpack8(const uint4 u, float* f){
  f[0]=bflo(u.x); f[1]=bfhi(u.x); f[2]=bflo(u.y); f[3]=bfhi(u.y);
  f[4]=bflo(u.z); f[5]=bfhi(u.z); f[6]=bflo(u.w); f[7]=bfhi(u.w);
}
// load 8 f32, return packed bf16 (4 u32)
__device__ __forceinline__ uint4 loadpack8(const float* __restrict__ p){
  float4 a = *(const float4*)p, b = *(const float4*)(p + 4);
  return make_uint4(pack2(a.x,a.y),pack2(a.z,a.w),pack2(b.x,b.y),pack2(b.z,b.w));
}
__device__ __forceinline__ float dot16(const float* __restrict__ yn,
                                       const float* __restrict__ row){
  float4 W0 = *(const float4*)row;
  float4 W1 = *(const float4*)(row + 4);
  float4 W2 = *(const float4*)(row + 8);
  float4 W3 = *(const float4*)(row + 12);
  float d = 0.f;
  d = fmaf(yn[0],W0.x,d); d = fmaf(yn[1],W0.y,d);
  d = fmaf(yn[2],W0.z,d); d = fmaf(yn[3],W0.w,d);
  d = fmaf(yn[4],W1.x,d); d = fmaf(yn[5],W1.y,d);
  d = fmaf(yn[6],W1.z,d); d = fmaf(yn[7],W1.w,d);
  d = fmaf(yn[8],W2.x,d); d = fmaf(yn[9],W2.y,d);
  d = fmaf(yn[10],W2.z,d); d = fmaf(yn[11],W2.w,d);
  d = fmaf(yn[12],W3.x,d); d = fmaf(yn[13],W3.y,d);
  d = fmaf(yn[14],W3.z,d); d = fmaf(yn[15],W3.w,d);
  return d;
}
__device__ __forceinline__ float rsum16(float v){
  v += __shfl_xor(v, 1);
  v += __shfl_xor(v, 2);
  v += __shfl_xor(v, 4);
  v += __shfl_xor(v, 8);
  return v;
}

// batch accessor: int32 or int64 (little-endian low word)
__device__ __forceinline__ int getb(const int* __restrict__ b, int is64, int i){
  return b[is64 ? 2*i : i];
}

// =====================================================================
// K0: detect batch int-width (parallel).
// =====================================================================
__global__ __launch_bounds__(256) void k_detect(
    const int* __restrict__ batch, int n, int* __restrict__ flags)
{
  int i = blockIdx.x*256 + threadIdx.x;
  int bad = 0;
  if (i < n - 1 && batch[i] > batch[i + 1]) bad = 1;
  if (__builtin_amdgcn_ballot_w64(bad) != 0 && (threadIdx.x & 63) == 0)
    atomicOr(&flags[0], 1);
}

// =====================================================================
// K0b: CSR bounds. bounds[g] = first node of graph g; bounds[B] = N.
// =====================================================================
__global__ __launch_bounds__(256) void k_bounds(
    const int* __restrict__ batch, const int* __restrict__ flags,
    int N, int B, int* __restrict__ bounds)
{
  int i = blockIdx.x*256 + threadIdx.x;
  if (i >= N) return;
  const int is64 = flags[0];
  int b = getb(batch, is64, i);
  int prev = (i == 0) ? -1 : getb(batch, is64, i - 1);
  for (int g = prev + 1; g <= b; g++) bounds[g] = i;
  if (i == N - 1)
    for (int g = b + 1; g <= B; g++) bounds[g] = N;
}

// =====================================================================
// K1 (fused MFMA GEMM + GroupNorm + grouped QKV convs).
// Tile 128 nodes x 64 cols (= 4 complete groups).
// Conv phase: wave w = group w (wave-uniform weight broadcast);
// ynL rows padded to 74 u16 (stride-5 banks -> 2-way = free).
// =====================================================================
__global__ __launch_bounds__(256) void k_prefused(
    const float* __restrict__ x, const float* __restrict__ wpre,
    const float* __restrict__ bpre,
    const float* __restrict__ wq, const float* __restrict__ wk,
    const float* __restrict__ wv,
    u16* __restrict__ qo, u16* __restrict__ ko, u16* __restrict__ vo,
    int N, int nbm)
{
  __shared__ __align__(16) char SMEM[25600];    // As/Bs (15.3K) then wL (25K)
  __shared__ __align__(16) u16 ynL[128*74];     // 18.5 KB
  u16* As = (u16*)SMEM;                         // 128*40
  u16* Bs = (u16*)(SMEM + 128*40*2);            // 64*40
  float* wL = (float*)SMEM;                     // 3*2080 f32 after barrier

  const int t = threadIdx.x;
  const int bm = blockIdx.x % nbm;
  const int bn = blockIdx.x / nbm;              // 0..3
  const int m_base = bm*128, n_base = bn*64;
  const int w = t >> 6, lane = t & 63;
  const int wr = (w >> 1)*64, wc = (w & 1)*32;
  const int fr = lane & 15, fk = lane >> 4;
  const int arow = t >> 1, acol = (t & 1)*16;
  const int brow = t >> 2, bcol = (t & 3)*8;

  v4f acc[4][2];
#pragma unroll
  for (int i = 0; i < 4; i++)
#pragma unroll
    for (int j = 0; j < 2; j++) acc[i][j] = (v4f){0.f,0.f,0.f,0.f};

  for (int k0 = 0; k0 < 256; k0 += 32) {
    __syncthreads();
    {
      int gm = m_base + arow;
      uint4 a0 = make_uint4(0u,0u,0u,0u), a1 = make_uint4(0u,0u,0u,0u);
      if (gm < N) {
        a0 = loadpack8(x + (size_t)gm*256 + k0 + acol);
        a1 = loadpack8(x + (size_t)gm*256 + k0 + acol + 8);
      }
      *(uint4*)&As[arow*40 + acol]     = a0;
      *(uint4*)&As[arow*40 + acol + 8] = a1;
      uint4 bv = loadpack8(wpre + (size_t)(n_base + brow)*256 + k0 + bcol);
      *(uint4*)&Bs[brow*40 + bcol] = bv;
    }
    __syncthreads();
    v8s b0 = *(const v8s*)&Bs[(wc      + fr)*40 + fk*8];
    v8s b1 = *(const v8s*)&Bs[(wc + 16 + fr)*40 + fk*8];
#pragma unroll
    for (int mi = 0; mi < 4; mi++) {
      v8s a = *(const v8s*)&As[(wr + mi*16 + fr)*40 + fk*8];
      acc[mi][0] = __builtin_amdgcn_mfma_f32_16x16x32_bf16(a,b0,acc[mi][0],0,0,0);
      acc[mi][1] = __builtin_amdgcn_mfma_f32_16x16x32_bf16(a,b1,acc[mi][1],0,0,0);
    }
  }

  // ---- epilogue: GroupNorm in-register, yn -> ynL ----
#pragma unroll
  for (int nj = 0; nj < 2; nj++) {
    int col = n_base + wc + nj*16 + fr;
    float bpv = bpre[col];
    int gloc = (w & 1)*2 + nj;                  // group within tile 0..3
#pragma unroll
    for (int mi = 0; mi < 4; mi++) {
#pragma unroll
      for (int r = 0; r < 4; r++) {
        float yv = acc[mi][nj][r] + bpv;
        float s1 = rsum16(yv);
        float s2 = rsum16(yv*yv);
        float mu = s1 * 0.0625f;
        float var = fmaxf(s2*0.0625f - mu*mu, 0.f);
        float ynv = (yv - mu) * rsqrtf(var + GN_EPS);
        int row = wr + mi*16 + fk*4 + r;        // 0..127
        ynL[row*74 + gloc*16 + fr] = f2bf(ynv);
      }
    }
  }
  __syncthreads();   // MFMA LDS reads done; ynL published

  // ---- stage qkv weights for this tile's 4 groups (over As/Bs) ----
  {
    const float* srcs[3] = {wq, wk, wv};
#pragma unroll
    for (int tz = 0; tz < 3; tz++) {
      for (int i = t; i < 2048; i += 256) {
        int gi = i >> 9, rem = i & 511;
        wL[tz*2080 + gi*520 + rem] = srcs[tz][((size_t)(bn*4 + gi))*512 + rem];
      }
    }
  }
  __syncthreads();

  // ---- conv phase: wave w = group w (wave-uniform weights) ----
  u16* outs[3] = {qo, ko, vo};
  const int gl = w;                             // 4 waves, 4 groups
  const int g  = bn*4 + gl;
#pragma unroll
  for (int p = 0; p < 2; p++) {
    int nloc = p*64 + lane;
    int node = m_base + nloc;
    if (node >= N) continue;
    u32 yw[8];
#pragma unroll
    for (int j = 0; j < 8; j++)
      yw[j] = *(const u32*)&ynL[nloc*74 + gl*16 + j*2];
    float yn[16];
#pragma unroll
    for (int j = 0; j < 8; j++) { yn[2*j] = bflo(yw[j]); yn[2*j+1] = bfhi(yw[j]); }
#pragma unroll
    for (int tz = 0; tz < 3; tz++) {
#pragma unroll
      for (int s = 0; s < 2; s++) {
        u32 pk[8];
#pragma unroll
        for (int o = 0; o < 16; o++) {
          float d = dot16(yn, &wL[tz*2080 + gl*520 + (s*16 + o)*16]);
          if (tz < 2) d = __expf(d*0.25f);
          if (o & 1) pk[o>>1] |= (u32)f2bf(d) << 16;
          else       pk[o>>1]  = (u32)f2bf(d);
        }
        u16* dst = outs[tz] + (size_t)node*512 + g*32 + s*16;
        *(uint4*)dst       = make_uint4(pk[0],pk[1],pk[2],pk[3]);
        *(uint4*)(dst + 8) = make_uint4(pk[4],pk[5],pk[6],pk[7]);
      }
    }
  }
}

// =====================================================================
// K3 (512 threads, fused, reduction-free): thread (nh, d) owns output
// row KV[nh][d][0:16] and k_sum[nh][d]; accumulates over ALL graph
// nodes. Phase 2: out1 = KV + xres; kv -> LDS bf16. Phase 3: att.
// =====================================================================
__global__ __launch_bounds__(512) void k_segatt(
    const u16* __restrict__ xk, const u16* __restrict__ xv,
    const u16* __restrict__ xq, const float* __restrict__ xres,
    const int* __restrict__ bounds,
    float* __restrict__ out1, u16* __restrict__ att, int N)
{
  __shared__ __align__(16) u16 kvs[32*280];     // 17.5 KB
  __shared__ float kss[32*17];                  // 2.2 KB
  const int b = blockIdx.x, t = threadIdx.x;
  const int lo = bounds[b], hi = bounds[b+1];
  const int nh = t >> 4, d = t & 15;

  float kv[16];
#pragma unroll
  for (int v = 0; v < 16; v++) kv[v] = 0.f;
  float ks = 0.f;

  const size_t koff = (size_t)nh*16 + d;
  const size_t voff = (size_t)nh*16;
  int node = lo;
  for (; node + 1 < hi; node += 2) {
    u16  ka  = xk[(size_t)node*512 + koff];
    uint4 Va0 = *(const uint4*)(xv + (size_t)node*512 + voff);
    uint4 Va1 = *(const uint4*)(xv + (size_t)node*512 + voff + 8);
    u16  kb  = xk[(size_t)(node+1)*512 + koff];
    uint4 Vb0 = *(const uint4*)(xv + (size_t)(node+1)*512 + voff);
    uint4 Vb1 = *(const uint4*)(xv + (size_t)(node+1)*512 + voff + 8);
    float k0 = bf1(ka), k1 = bf1(kb);
    float va[16], vb[16];
    unpack8(Va0, va); unpack8(Va1, va + 8);
    unpack8(Vb0, vb); unpack8(Vb1, vb + 8);
    ks += k0 + k1;
#pragma unroll
    for (int v = 0; v < 16; v++) {
      kv[v] = fmaf(k0, va[v], kv[v]);
      kv[v] = fmaf(k1, vb[v], kv[v]);
    }
  }
  if (node < hi) {
    u16  ka  = xk[(size_t)node*512 + koff];
    uint4 V0 = *(const uint4*)(xv + (size_t)node*512 + voff);
    uint4 V1 = *(const uint4*)(xv + (size_t)node*512 + voff + 8);
    float k0 = bf1(ka);
    float vf[16]; unpack8(V0, vf); unpack8(V1, vf + 8);
    ks += k0;
#pragma unroll
    for (int v = 0; v < 16; v++) kv[v] = fmaf(k0, vf[v], kv[v]);
  }

  kss[nh*17 + d] = ks;

  {
    size_t idx = ((size_t)(b*32 + nh)*16 + d)*16;
    const float* xp = xres + idx;
    float4 X0 = *(const float4*)xp;
    float4 X1 = *(const float4*)(xp + 4);
    float4 X2 = *(const float4*)(xp + 8);
    float4 X3 = *(const float4*)(xp + 12);
    float xf[16] = {X0.x,X0.y,X0.z,X0.w,X1.x,X1.y,X1.z,X1.w,
                    X2.x,X2.y,X2.z,X2.w,X3.x,X3.y,X3.z,X3.w};
    float o[16];
#pragma unroll
    for (int j = 0; j < 16; j++) o[j] = kv[j] + xf[j];
    float* op = out1 + idx;
    *(float4*)op        = make_float4(o[0],o[1],o[2],o[3]);
    *(float4*)(op + 4)  = make_float4(o[4],o[5],o[6],o[7]);
    *(float4*)(op + 8)  = make_float4(o[8],o[9],o[10],o[11]);
    *(float4*)(op + 12) = make_float4(o[12],o[13],o[14],o[15]);
    u16* lp = &kvs[nh*280 + d*16];
    *(uint4*)lp       = make_uint4(pack2(o[0],o[1]),  pack2(o[2],o[3]),
                                   pack2(o[4],o[5]),  pack2(o[6],o[7]));
    *(uint4*)(lp + 8) = make_uint4(pack2(o[8],o[9]),  pack2(o[10],o[11]),
                                   pack2(o[12],o[13]),pack2(o[14],o[15]));
  }
  __syncthreads();

  const int nh2 = t & 31, ns = t >> 5;   // ns 0..15
  for (int n0 = lo; n0 < hi; n0 += 16) {
    int nodei = n0 + ns;
    if (nodei >= hi) continue;
    const u16* qp = xq + (size_t)nodei*512 + nh2*16;
    uint4 Q0 = *(const uint4*)qp;
    uint4 Q1 = *(const uint4*)(qp + 8);
    float q[16]; unpack8(Q0, q); unpack8(Q1, q + 8);
    const float* ksp = &kss[nh2*17];
    float denom = 0.f;
#pragma unroll
    for (int i = 0; i < 16; i++) denom = fmaf(q[i], ksp[i], denom);
    float inv = 1.0f / fmaxf(denom, 1e-20f);
    float a[16];
#pragma unroll
    for (int v = 0; v < 16; v++) a[v] = 0.f;
    const u16* kvp = &kvs[nh2*280];
#pragma unroll
    for (int h = 0; h < 16; h++) {
      float qh = q[h] * inv;
      uint4 W0 = *(const uint4*)(kvp + h*16);
      uint4 W1 = *(const uint4*)(kvp + h*16 + 8);
      float wv2[16]; unpack8(W0, wv2); unpack8(W1, wv2 + 8);
#pragma unroll
      for (int v = 0; v < 16; v++) a[v] = fmaf(qh, wv2[v], a[v]);
    }
    u32 p[8];
#pragma unroll
    for (int j = 0; j < 8; j++) p[j] = pack2(a[2*j], a[2*j+1]);
    u16* dst = att + (size_t)nodei*512 + nh2*16;
    *(uint4*)dst       = make_uint4(p[0],p[1],p[2],p[3]);
    *(uint4*)(dst + 8) = make_uint4(p[4],p[5],p[6],p[7]);
  }
}

// =====================================================================
// K5 (MFMA): out0 = exp(log_scale) * (att @ w_post^T + b_post), K=512.
// Tile 128x64.
// =====================================================================
__global__ __launch_bounds__(256) void k_post(
    const u16* __restrict__ att, const float* __restrict__ wpost,
    const float* __restrict__ bpost, const float* __restrict__ ls,
    float* __restrict__ out0, int N, int nbm)
{
  __shared__ __align__(16) u16 As[128*40];
  __shared__ __align__(16) u16 Bs[64*40];
  const int t = threadIdx.x;
  const int bm = blockIdx.x % nbm;
  const int bn = blockIdx.x / nbm;          // 0..3
  const int m_base = bm*128, n_base = bn*64;
  const int w = t >> 6, lane = t & 63;
  const int wr = (w >> 1)*64, wc = (w & 1)*32;
  const int fr = lane & 15, fk = lane >> 4;
  const int arow = t >> 1, acol = (t & 1)*16;
  const int brow = t >> 2, bcol = (t & 3)*8;

  v4f acc[4][2];
#pragma unroll
  for (int i = 0; i < 4; i++)
#pragma unroll
    for (int j = 0; j < 2; j++) acc[i][j] = (v4f){0.f,0.f,0.f,0.f};

  for (int k0 = 0; k0 < 512; k0 += 32) {
    __syncthreads();
    {
      int gm = m_base + arow;
      uint4 a0 = make_uint4(0u,0u,0u,0u), a1 = make_uint4(0u,0u,0u,0u);
      if (gm < N) {
        a0 = *(const uint4*)(att + (size_t)gm*512 + k0 + acol);
        a1 = *(const uint4*)(att + (size_t)gm*512 + k0 + acol + 8);
      }
      *(uint4*)&As[arow*40 + acol]     = a0;
      *(uint4*)&As[arow*40 + acol + 8] = a1;
      uint4 bv = loadpack8(wpost + (size_t)(n_base + brow)*512 + k0 + bcol);
      *(uint4*)&Bs[brow*40 + bcol] = bv;
    }
    __syncthreads();
    v8s b0 = *(const v8s*)&Bs[(wc      + fr)*40 + fk*8];
    v8s b1 = *(const v8s*)&Bs[(wc + 16 + fr)*40 + fk*8];
#pragma unroll
    for (int mi = 0; mi < 4; mi++) {
      v8s a = *(const v8s*)&As[(wr + mi*16 + fr)*40 + fk*8];
      acc[mi][0] = __builtin_amdgcn_mfma_f32_16x16x32_bf16(a,b0,acc[mi][0],0,0,0);
      acc[mi][1] = __builtin_amdgcn_mfma_f32_16x16x32_bf16(a,b1,acc[mi][1],0,0,0);
    }
  }
#pragma unroll
  for (int nj = 0; nj < 2; nj++) {
    int col = n_base + wc + nj*16 + fr;
    float bpv = bpost[col];
    float e   = __expf(ls[col]);
#pragma unroll
    for (int mi = 0; mi < 4; mi++) {
#pragma unroll
      for (int r = 0; r < 4; r++) {
        int row = m_base + wr + mi*16 + fk*4 + r;
        if (row < N) out0[(size_t)row*256 + col] = e*(acc[mi][nj][r] + bpv);
      }
    }
  }
}

// =====================================================================
extern "C" void kernel_launch(void* const* d_in, const int* in_sizes, int n_in,
                              void* d_out, int out_size, void* d_ws, size_t ws_size,
                              hipStream_t stream)
{
  const float* x     = (const float*)d_in[0];
  const float* xres  = (const float*)d_in[1];
  const int*   batch = (const int*)d_in[2];
  const float* wpre  = (const float*)d_in[4];
  const float* bpre  = (const float*)d_in[5];
  const float* wq    = (const float*)d_in[6];
  const float* wk    = (const float*)d_in[7];
  const float* wv    = (const float*)d_in[8];
  const float* wpost = (const float*)d_in[9];
  const float* bpost = (const float*)d_in[10];
  const float* ls    = (const float*)d_in[11];

  const int N = in_sizes[0] / 256;     // 20000 nodes
  const int B = in_sizes[1] / 8192;    // 1024 graphs
  const int nbm = (N + 127) / 128;     // 157 row tiles
  const int nchunk = (N + 255) / 256;  // 79 node chunks

  char* ws = (char*)d_ws;
  size_t off = 0;
  int*   flags  = (int*)(ws + off); off += 256;
  int*   bounds = (int*)(ws + off); off += ((size_t)B + 64) * 4;
  u16*   att    = (u16*)(ws + off);  off += (size_t)N * 1024;
  u16*   q      = (u16*)(ws + off);  off += (size_t)N * 1024;
  u16*   kten   = (u16*)(ws + off);  off += (size_t)N * 1024;
  u16*   vten   = (u16*)(ws + off);  off += (size_t)N * 1024;

  float* out0 = (float*)d_out;
  float* out1 = out0 + (size_t)N * 256;

  hipMemsetAsync(flags, 0, 4, stream);
  k_detect  <<<nchunk,        256, 0, stream>>>(batch, N, flags);
  k_bounds  <<<nchunk,        256, 0, stream>>>(batch, flags, N, B, bounds);
  k_prefused<<<nbm * 4,       256, 0, stream>>>(x, wpre, bpre, wq, wk, wv,
                                                q, kten, vten, N, nbm);
  k_segatt  <<<B,             512, 0, stream>>>(kten, vten, q, xres, bounds,
                                                out1, att, N);
  k_post    <<<nbm * 4,       256, 0, stream>>>(att, wpost, bpost, ls, out0, N, nbm);
}